// Round 1
// baseline (718.293 us; speedup 1.0000x reference)
//
#include <hip/hip_runtime.h>
#include <math.h>

#define NN 50000
#define EE 1600000
#define FIN 128
#define FOUT 128   // HEADS*HID
#define NEG 0.2f
#define BNEPS 1e-5f

// ---------------- conv1 projection + attention logits ----------------
__global__ __launch_bounds__(256) void k_proj(const float* __restrict__ x,
    const float* __restrict__ W1, const float* __restrict__ asw, const float* __restrict__ adw,
    float* __restrict__ h, float* __restrict__ as1, float* __restrict__ ad1) {
  int t = threadIdx.x;
  int n = blockIdx.x * 2 + (t >> 7);   // 2 nodes per 256-thread block
  int c = t & 127;
  const float* xr = x + (size_t)n * FIN;
  float acc = 0.f;
  #pragma unroll 8
  for (int k = 0; k < FIN; ++k) acc = fmaf(xr[k], W1[k * FOUT + c], acc);
  h[(size_t)n * FOUT + c] = acc;
  int head = c >> 5, ch = c & 31;
  float vs = acc * asw[c];   // att_src1 flattened [head*32+ch] == [c]
  float vd = acc * adw[c];
  #pragma unroll
  for (int m = 16; m >= 1; m >>= 1) { vs += __shfl_xor(vs, m, 64); vd += __shfl_xor(vd, m, 64); }
  if (ch == 0) { as1[n * 4 + head] = vs; ad1[n * 4 + head] = vd; }
}

// ---------------- CSR build (by dst) ----------------
__global__ __launch_bounds__(256) void k_init(int* __restrict__ deg) {
  int i = blockIdx.x * 256 + threadIdx.x;
  if (i < NN) deg[i] = 1;   // self loop
}

__global__ __launch_bounds__(256) void k_hist(const int* __restrict__ ei, int* __restrict__ deg) {
  int i = blockIdx.x * 256 + threadIdx.x;
  if (i < EE) atomicAdd(&deg[ei[EE + i]], 1);   // dst row of edge_index
}

__global__ __launch_bounds__(1024) void k_scan(const int* __restrict__ deg,
    int* __restrict__ offs, int* __restrict__ cur) {
  __shared__ int sums[1024];
  int t = threadIdx.x;
  const int CH = (NN + 1023) / 1024;  // 49
  int base = t * CH;
  int s = 0;
  for (int i = 0; i < CH; ++i) { int idx = base + i; if (idx < NN) s += deg[idx]; }
  sums[t] = s; __syncthreads();
  for (int off = 1; off < 1024; off <<= 1) {
    int v = (t >= off) ? sums[t - off] : 0;
    __syncthreads();
    sums[t] += v;
    __syncthreads();
  }
  int run = (t == 0) ? 0 : sums[t - 1];
  for (int i = 0; i < CH; ++i) {
    int idx = base + i;
    if (idx < NN) { offs[idx] = run; cur[idx] = run; run += deg[idx]; }
  }
  if (t == 1023) offs[NN] = sums[1023];   // total = EE + NN
}

__global__ __launch_bounds__(256) void k_scatter(const int* __restrict__ ei,
    int* __restrict__ cur, int* __restrict__ csr) {
  int i = blockIdx.x * 256 + threadIdx.x;
  if (i >= EE + NN) return;
  int s, d;
  if (i < EE) { s = ei[i]; d = ei[EE + i]; }
  else        { s = d = i - EE; }          // self loops
  int p = atomicAdd(&cur[d], 1);
  csr[p] = s;
}

// ---------------- conv1 aggregation + bias + BN + leaky + conv2 projection ----------------
__global__ __launch_bounds__(256) void k_agg1(
    const int* __restrict__ offs, const int* __restrict__ csr,
    const float* __restrict__ h, const float* __restrict__ as1, const float* __restrict__ ad1,
    const float* __restrict__ bias1, const float* __restrict__ gamma, const float* __restrict__ beta,
    const float* __restrict__ mean, const float* __restrict__ var,
    const float* __restrict__ W2, const float* __restrict__ asw2, const float* __restrict__ adw2,
    float* __restrict__ h2, float* __restrict__ as2, float* __restrict__ ad2) {
  int wid = threadIdx.x >> 6;
  int lane = threadIdx.x & 63;
  int n = blockIdx.x * 4 + wid;
  if (n >= NN) return;
  int r0 = offs[n], r1 = offs[n + 1];
  int c1 = lane, c2 = lane + 64;
  int hA = c1 >> 5;          // 0 or 1
  int hB = c2 >> 5;          // 2 or 3
  float4 adv = *(const float4*)(ad1 + n * 4);

  // pass 1: per-head segment max (lanes split edges)
  float m0 = -1e30f, m1 = -1e30f, m2 = -1e30f, m3 = -1e30f;
  for (int i = r0 + lane; i < r1; i += 64) {
    int s = csr[i];
    float4 as = *(const float4*)(as1 + s * 4);
    float e;
    e = as.x + adv.x; e = e > 0.f ? e : NEG * e; m0 = fmaxf(m0, e);
    e = as.y + adv.y; e = e > 0.f ? e : NEG * e; m1 = fmaxf(m1, e);
    e = as.z + adv.z; e = e > 0.f ? e : NEG * e; m2 = fmaxf(m2, e);
    e = as.w + adv.w; e = e > 0.f ? e : NEG * e; m3 = fmaxf(m3, e);
  }
  #pragma unroll
  for (int mm = 32; mm >= 1; mm >>= 1) {
    m0 = fmaxf(m0, __shfl_xor(m0, mm, 64));
    m1 = fmaxf(m1, __shfl_xor(m1, mm, 64));
    m2 = fmaxf(m2, __shfl_xor(m2, mm, 64));
    m3 = fmaxf(m3, __shfl_xor(m3, mm, 64));
  }
  float mA = (hA == 0) ? m0 : m1;
  float mB = (hB == 2) ? m2 : m3;
  float adA = (hA == 0) ? adv.x : adv.y;
  float adB = (hB == 2) ? adv.z : adv.w;

  // pass 2: lanes own feature channels; iterate all edges
  float acc1 = 0.f, acc2 = 0.f, den1 = 0.f, den2 = 0.f;
  for (int i = r0; i < r1; ++i) {
    int s = csr[i];
    float asA = as1[s * 4 + hA];
    float asB = as1[s * 4 + hB];
    float eA = asA + adA; eA = eA > 0.f ? eA : NEG * eA;
    float eB = asB + adB; eB = eB > 0.f ? eB : NEG * eB;
    float exA = __expf(eA - mA);
    float exB = __expf(eB - mB);
    den1 += exA; den2 += exB;
    acc1 = fmaf(exA, h[(size_t)s * FOUT + c1], acc1);
    acc2 = fmaf(exB, h[(size_t)s * FOUT + c2], acc2);
  }

  // epilogue: /denom + bias1 + BN + leaky
  float o1 = acc1 / den1 + bias1[c1];
  float o2 = acc2 / den2 + bias1[c2];
  o1 = gamma[c1] * (o1 - mean[c1]) * rsqrtf(var[c1] + BNEPS) + beta[c1];
  o2 = gamma[c2] * (o2 - mean[c2]) * rsqrtf(var[c2] + BNEPS) + beta[c2];
  o1 = o1 > 0.f ? o1 : NEG * o1;
  o2 = o2 > 0.f ? o2 : NEG * o2;

  // conv2 projection: p = h1b @ W2  (reduce over 128 features across the wave)
  float p0 = o1 * W2[c1 * 2 + 0] + o2 * W2[c2 * 2 + 0];
  float p1 = o1 * W2[c1 * 2 + 1] + o2 * W2[c2 * 2 + 1];
  #pragma unroll
  for (int mm = 32; mm >= 1; mm >>= 1) {
    p0 += __shfl_xor(p0, mm, 64);
    p1 += __shfl_xor(p1, mm, 64);
  }
  if (lane == 0) {
    h2[n * 2 + 0] = p0;
    h2[n * 2 + 1] = p1;
    as2[n] = p0 * asw2[0] + p1 * asw2[1];
    ad2[n] = p0 * adw2[0] + p1 * adw2[1];
  }
}

// ---------------- conv2 aggregation + bias + log_softmax ----------------
__global__ __launch_bounds__(256) void k_agg2(
    const int* __restrict__ offs, const int* __restrict__ csr,
    const float* __restrict__ h2, const float* __restrict__ as2, const float* __restrict__ ad2,
    const float* __restrict__ bias2, float* __restrict__ out) {
  int wid = threadIdx.x >> 6;
  int lane = threadIdx.x & 63;
  int n = blockIdx.x * 4 + wid;
  if (n >= NN) return;
  int r0 = offs[n], r1 = offs[n + 1];
  float ad = ad2[n];

  float m = -1e30f;
  for (int i = r0 + lane; i < r1; i += 64) {
    float e = as2[csr[i]] + ad; e = e > 0.f ? e : NEG * e;
    m = fmaxf(m, e);
  }
  #pragma unroll
  for (int mm = 32; mm >= 1; mm >>= 1) m = fmaxf(m, __shfl_xor(m, mm, 64));

  float den = 0.f, a0 = 0.f, a1 = 0.f;
  for (int i = r0 + lane; i < r1; i += 64) {
    int s = csr[i];
    float e = as2[s] + ad; e = e > 0.f ? e : NEG * e;
    float ex = __expf(e - m);
    float2 hv = *(const float2*)(h2 + s * 2);
    den += ex;
    a0 = fmaf(ex, hv.x, a0);
    a1 = fmaf(ex, hv.y, a1);
  }
  #pragma unroll
  for (int mm = 32; mm >= 1; mm >>= 1) {
    den += __shfl_xor(den, mm, 64);
    a0  += __shfl_xor(a0, mm, 64);
    a1  += __shfl_xor(a1, mm, 64);
  }
  if (lane == 0) {
    float o0 = a0 / den + bias2[0];
    float o1 = a1 / den + bias2[1];
    float mx = fmaxf(o0, o1);
    float lse = mx + logf(__expf(o0 - mx) + __expf(o1 - mx));
    out[n * 2 + 0] = o0 - lse;
    out[n * 2 + 1] = o1 - lse;
  }
}

extern "C" void kernel_launch(void* const* d_in, const int* in_sizes, int n_in,
                              void* d_out, int out_size, void* d_ws, size_t ws_size,
                              hipStream_t stream) {
  const float* x     = (const float*)d_in[0];
  const int*   ei    = (const int*)d_in[1];
  const float* W1    = (const float*)d_in[2];
  const float* asw1  = (const float*)d_in[3];
  const float* adw1  = (const float*)d_in[4];
  const float* bias1 = (const float*)d_in[5];
  const float* gamma = (const float*)d_in[6];
  const float* beta  = (const float*)d_in[7];
  const float* mean  = (const float*)d_in[8];
  const float* var   = (const float*)d_in[9];
  const float* W2    = (const float*)d_in[10];
  const float* asw2  = (const float*)d_in[11];
  const float* adw2  = (const float*)d_in[12];
  const float* bias2 = (const float*)d_in[13];
  float* out = (float*)d_out;

  char* ws = (char*)d_ws;
  size_t off = 0;
  auto alloc = [&](size_t bytes) {
    void* p = ws + off;
    off += (bytes + 255) & ~(size_t)255;
    return p;
  };
  float* h    = (float*)alloc((size_t)NN * FOUT * 4);     // 25.6 MB
  float* as1  = (float*)alloc((size_t)NN * 4 * 4);
  float* ad1  = (float*)alloc((size_t)NN * 4 * 4);
  int*   deg  = (int*)alloc((size_t)NN * 4);
  int*   offs = (int*)alloc(((size_t)NN + 1) * 4);
  int*   cur  = (int*)alloc((size_t)NN * 4);
  int*   csr  = (int*)alloc((size_t)(EE + NN) * 4);       // 6.6 MB
  float* h2   = (float*)alloc((size_t)NN * 2 * 4);
  float* as2  = (float*)alloc((size_t)NN * 4);
  float* ad2  = (float*)alloc((size_t)NN * 4);
  (void)ws_size; (void)in_sizes; (void)n_in; (void)out_size;

  k_proj   <<<NN / 2, 256, 0, stream>>>(x, W1, asw1, adw1, h, as1, ad1);
  k_init   <<<(NN + 255) / 256, 256, 0, stream>>>(deg);
  k_hist   <<<(EE + 255) / 256, 256, 0, stream>>>(ei, deg);
  k_scan   <<<1, 1024, 0, stream>>>(deg, offs, cur);
  k_scatter<<<(EE + NN + 255) / 256, 256, 0, stream>>>(ei, cur, csr);
  k_agg1   <<<(NN + 3) / 4, 256, 0, stream>>>(offs, csr, h, as1, ad1, bias1, gamma, beta,
                                              mean, var, W2, asw2, adw2, h2, as2, ad2);
  k_agg2   <<<(NN + 3) / 4, 256, 0, stream>>>(offs, csr, h2, as2, ad2, bias2, out);
}

// Round 2
// 577.214 us; speedup vs baseline: 1.2444x; 1.2444x over previous
//
#include <hip/hip_runtime.h>
#include <math.h>

#define NN 50000
#define EE 1600000
#define FIN 128
#define FOUT 128   // HEADS*HID
#define NEG 0.2f
#define BNEPS 1e-5f

// ---------------- conv1 projection + attention logits (register-tiled GEMM) ----------------
// Block: 64 nodes x 128 channels. 256 threads, each computes 4 nodes x 8 channels.
#define XS_STRIDE 132  // pad 128 -> 132 floats: keeps 16B alignment, kills 4-way bank conflicts
__global__ __launch_bounds__(256) void k_proj(const float* __restrict__ x,
    const float* __restrict__ W1, const float* __restrict__ asw, const float* __restrict__ adw,
    float* __restrict__ h, float* __restrict__ as1, float* __restrict__ ad1) {
  __shared__ float xs[64 * XS_STRIDE];
  int t = threadIdx.x;
  int nb = blockIdx.x * 64;

  // stage x tile [64][128] -> LDS (coalesced float4)
  #pragma unroll
  for (int j = 0; j < 8; ++j) {
    int idx = t + 256 * j;          // 0..2047 float4 slots
    int r = idx >> 5;               // row 0..63
    int c4 = idx & 31;              // float4 col 0..31
    int n = nb + r; if (n >= NN) n = NN - 1;   // clamp tail (dup reads, never used for OOB writes)
    float4 v = *(const float4*)(x + (size_t)n * FIN + c4 * 4);
    *(float4*)(&xs[r * XS_STRIDE + c4 * 4]) = v;
  }
  __syncthreads();

  int cg = t & 15;        // channel group -> channels cg*8 .. cg*8+7 (all in head cg/4)
  int ng = t >> 4;        // node group   -> nodes ng*4 .. ng*4+3
  int c0 = cg * 8;

  float acc[4][8];
  #pragma unroll
  for (int i = 0; i < 4; ++i)
    #pragma unroll
    for (int j = 0; j < 8; ++j) acc[i][j] = 0.f;

  for (int k0 = 0; k0 < FIN; k0 += 4) {
    float xr[4][4];
    #pragma unroll
    for (int i = 0; i < 4; ++i)
      *(float4*)xr[i] = *(const float4*)&xs[(ng * 4 + i) * XS_STRIDE + k0];
    #pragma unroll
    for (int kk = 0; kk < 4; ++kk) {
      float4 w0 = *(const float4*)(W1 + (k0 + kk) * FOUT + c0);
      float4 w1 = *(const float4*)(W1 + (k0 + kk) * FOUT + c0 + 4);
      float wv[8] = {w0.x, w0.y, w0.z, w0.w, w1.x, w1.y, w1.z, w1.w};
      #pragma unroll
      for (int i = 0; i < 4; ++i) {
        float xv = xr[i][kk];
        #pragma unroll
        for (int j = 0; j < 8; ++j) acc[i][j] = fmaf(xv, wv[j], acc[i][j]);
      }
    }
  }

  // write h + attention logits
  int head = cg >> 2;
  float vs[4], vd[4];
  #pragma unroll
  for (int i = 0; i < 4; ++i) {
    int n = nb + ng * 4 + i;
    float s = 0.f, d = 0.f;
    #pragma unroll
    for (int j = 0; j < 8; ++j) {
      s = fmaf(acc[i][j], asw[c0 + j], s);
      d = fmaf(acc[i][j], adw[c0 + j], d);
    }
    vs[i] = s; vd[i] = d;
    if (n < NN) {
      *(float4*)(h + (size_t)n * FOUT + c0)     = make_float4(acc[i][0], acc[i][1], acc[i][2], acc[i][3]);
      *(float4*)(h + (size_t)n * FOUT + c0 + 4) = make_float4(acc[i][4], acc[i][5], acc[i][6], acc[i][7]);
    }
  }
  // reduce logits over the 4 channel-groups of this head (lanes differ in bits 0,1 of t)
  #pragma unroll
  for (int i = 0; i < 4; ++i) {
    vs[i] += __shfl_xor(vs[i], 1, 64); vs[i] += __shfl_xor(vs[i], 2, 64);
    vd[i] += __shfl_xor(vd[i], 1, 64); vd[i] += __shfl_xor(vd[i], 2, 64);
  }
  if ((cg & 3) == 0) {
    #pragma unroll
    for (int i = 0; i < 4; ++i) {
      int n = nb + ng * 4 + i;
      if (n < NN) { as1[n * 4 + head] = vs[i]; ad1[n * 4 + head] = vd[i]; }
    }
  }
}

// ---------------- CSR build (by dst) ----------------
__global__ __launch_bounds__(256) void k_init(int* __restrict__ deg) {
  int i = blockIdx.x * 256 + threadIdx.x;
  if (i < NN) deg[i] = 1;   // self loop
}

__global__ __launch_bounds__(256) void k_hist(const int* __restrict__ ei, int* __restrict__ deg) {
  int i = blockIdx.x * 256 + threadIdx.x;
  if (i < EE) atomicAdd(&deg[ei[EE + i]], 1);   // dst row of edge_index
}

__global__ __launch_bounds__(1024) void k_scan(const int* __restrict__ deg,
    int* __restrict__ offs, int* __restrict__ cur) {
  __shared__ int sums[1024];
  int t = threadIdx.x;
  const int CH = (NN + 1023) / 1024;  // 49
  int base = t * CH;
  int s = 0;
  for (int i = 0; i < CH; ++i) { int idx = base + i; if (idx < NN) s += deg[idx]; }
  sums[t] = s; __syncthreads();
  for (int off = 1; off < 1024; off <<= 1) {
    int v = (t >= off) ? sums[t - off] : 0;
    __syncthreads();
    sums[t] += v;
    __syncthreads();
  }
  int run = (t == 0) ? 0 : sums[t - 1];
  for (int i = 0; i < CH; ++i) {
    int idx = base + i;
    if (idx < NN) { offs[idx] = run; cur[idx] = run; run += deg[idx]; }
  }
  if (t == 1023) offs[NN] = sums[1023];   // total = EE + NN
}

__global__ __launch_bounds__(256) void k_scatter(const int* __restrict__ ei,
    int* __restrict__ cur, int* __restrict__ csr) {
  int i = blockIdx.x * 256 + threadIdx.x;
  if (i >= EE + NN) return;
  int s, d;
  if (i < EE) { s = ei[i]; d = ei[EE + i]; }
  else        { s = d = i - EE; }          // self loops
  int p = atomicAdd(&cur[d], 1);
  csr[p] = s;
}

// ---------------- conv1 aggregation + bias + BN + leaky + conv2 projection ----------------
__global__ __launch_bounds__(256) void k_agg1(
    const int* __restrict__ offs, const int* __restrict__ csr,
    const float* __restrict__ h, const float* __restrict__ as1, const float* __restrict__ ad1,
    const float* __restrict__ bias1, const float* __restrict__ gamma, const float* __restrict__ beta,
    const float* __restrict__ mean, const float* __restrict__ var,
    const float* __restrict__ W2, const float* __restrict__ asw2, const float* __restrict__ adw2,
    float* __restrict__ h2, float* __restrict__ as2, float* __restrict__ ad2) {
  int wid = threadIdx.x >> 6;
  int lane = threadIdx.x & 63;
  int n = blockIdx.x * 4 + wid;
  if (n >= NN) return;
  int r0 = offs[n], r1 = offs[n + 1];
  int c1 = lane, c2 = lane + 64;
  int hA = c1 >> 5;          // 0 or 1
  int hB = c2 >> 5;          // 2 or 3
  float4 adv = *(const float4*)(ad1 + n * 4);

  // pass 1: per-head segment max (lanes split edges)
  float m0 = -1e30f, m1 = -1e30f, m2 = -1e30f, m3 = -1e30f;
  for (int i = r0 + lane; i < r1; i += 64) {
    int s = csr[i];
    float4 as = *(const float4*)(as1 + s * 4);
    float e;
    e = as.x + adv.x; e = e > 0.f ? e : NEG * e; m0 = fmaxf(m0, e);
    e = as.y + adv.y; e = e > 0.f ? e : NEG * e; m1 = fmaxf(m1, e);
    e = as.z + adv.z; e = e > 0.f ? e : NEG * e; m2 = fmaxf(m2, e);
    e = as.w + adv.w; e = e > 0.f ? e : NEG * e; m3 = fmaxf(m3, e);
  }
  #pragma unroll
  for (int mm = 32; mm >= 1; mm >>= 1) {
    m0 = fmaxf(m0, __shfl_xor(m0, mm, 64));
    m1 = fmaxf(m1, __shfl_xor(m1, mm, 64));
    m2 = fmaxf(m2, __shfl_xor(m2, mm, 64));
    m3 = fmaxf(m3, __shfl_xor(m3, mm, 64));
  }
  float mA = (hA == 0) ? m0 : m1;
  float mB = (hB == 2) ? m2 : m3;
  float adA = (hA == 0) ? adv.x : adv.y;
  float adB = (hB == 2) ? adv.z : adv.w;

  // pass 2: lanes own feature channels; iterate all edges
  float acc1 = 0.f, acc2 = 0.f, den1 = 0.f, den2 = 0.f;
  for (int i = r0; i < r1; ++i) {
    int s = csr[i];
    float asA = as1[s * 4 + hA];
    float asB = as1[s * 4 + hB];
    float eA = asA + adA; eA = eA > 0.f ? eA : NEG * eA;
    float eB = asB + adB; eB = eB > 0.f ? eB : NEG * eB;
    float exA = __expf(eA - mA);
    float exB = __expf(eB - mB);
    den1 += exA; den2 += exB;
    acc1 = fmaf(exA, h[(size_t)s * FOUT + c1], acc1);
    acc2 = fmaf(exB, h[(size_t)s * FOUT + c2], acc2);
  }

  // epilogue: /denom + bias1 + BN + leaky
  float o1 = acc1 / den1 + bias1[c1];
  float o2 = acc2 / den2 + bias1[c2];
  o1 = gamma[c1] * (o1 - mean[c1]) * rsqrtf(var[c1] + BNEPS) + beta[c1];
  o2 = gamma[c2] * (o2 - mean[c2]) * rsqrtf(var[c2] + BNEPS) + beta[c2];
  o1 = o1 > 0.f ? o1 : NEG * o1;
  o2 = o2 > 0.f ? o2 : NEG * o2;

  // conv2 projection: p = h1b @ W2  (reduce over 128 features across the wave)
  float p0 = o1 * W2[c1 * 2 + 0] + o2 * W2[c2 * 2 + 0];
  float p1 = o1 * W2[c1 * 2 + 1] + o2 * W2[c2 * 2 + 1];
  #pragma unroll
  for (int mm = 32; mm >= 1; mm >>= 1) {
    p0 += __shfl_xor(p0, mm, 64);
    p1 += __shfl_xor(p1, mm, 64);
  }
  if (lane == 0) {
    h2[n * 2 + 0] = p0;
    h2[n * 2 + 1] = p1;
    as2[n] = p0 * asw2[0] + p1 * asw2[1];
    ad2[n] = p0 * adw2[0] + p1 * adw2[1];
  }
}

// ---------------- conv2 aggregation + bias + log_softmax ----------------
__global__ __launch_bounds__(256) void k_agg2(
    const int* __restrict__ offs, const int* __restrict__ csr,
    const float* __restrict__ h2, const float* __restrict__ as2, const float* __restrict__ ad2,
    const float* __restrict__ bias2, float* __restrict__ out) {
  int wid = threadIdx.x >> 6;
  int lane = threadIdx.x & 63;
  int n = blockIdx.x * 4 + wid;
  if (n >= NN) return;
  int r0 = offs[n], r1 = offs[n + 1];
  float ad = ad2[n];

  float m = -1e30f;
  for (int i = r0 + lane; i < r1; i += 64) {
    float e = as2[csr[i]] + ad; e = e > 0.f ? e : NEG * e;
    m = fmaxf(m, e);
  }
  #pragma unroll
  for (int mm = 32; mm >= 1; mm >>= 1) m = fmaxf(m, __shfl_xor(m, mm, 64));

  float den = 0.f, a0 = 0.f, a1 = 0.f;
  for (int i = r0 + lane; i < r1; i += 64) {
    int s = csr[i];
    float e = as2[s] + ad; e = e > 0.f ? e : NEG * e;
    float ex = __expf(e - m);
    float2 hv = *(const float2*)(h2 + s * 2);
    den += ex;
    a0 = fmaf(ex, hv.x, a0);
    a1 = fmaf(ex, hv.y, a1);
  }
  #pragma unroll
  for (int mm = 32; mm >= 1; mm >>= 1) {
    den += __shfl_xor(den, mm, 64);
    a0  += __shfl_xor(a0, mm, 64);
    a1  += __shfl_xor(a1, mm, 64);
  }
  if (lane == 0) {
    float o0 = a0 / den + bias2[0];
    float o1 = a1 / den + bias2[1];
    float mx = fmaxf(o0, o1);
    float lse = mx + logf(__expf(o0 - mx) + __expf(o1 - mx));
    out[n * 2 + 0] = o0 - lse;
    out[n * 2 + 1] = o1 - lse;
  }
}

extern "C" void kernel_launch(void* const* d_in, const int* in_sizes, int n_in,
                              void* d_out, int out_size, void* d_ws, size_t ws_size,
                              hipStream_t stream) {
  const float* x     = (const float*)d_in[0];
  const int*   ei    = (const int*)d_in[1];
  const float* W1    = (const float*)d_in[2];
  const float* asw1  = (const float*)d_in[3];
  const float* adw1  = (const float*)d_in[4];
  const float* bias1 = (const float*)d_in[5];
  const float* gamma = (const float*)d_in[6];
  const float* beta  = (const float*)d_in[7];
  const float* mean  = (const float*)d_in[8];
  const float* var   = (const float*)d_in[9];
  const float* W2    = (const float*)d_in[10];
  const float* asw2  = (const float*)d_in[11];
  const float* adw2  = (const float*)d_in[12];
  const float* bias2 = (const float*)d_in[13];
  float* out = (float*)d_out;

  char* ws = (char*)d_ws;
  size_t off = 0;
  auto alloc = [&](size_t bytes) {
    void* p = ws + off;
    off += (bytes + 255) & ~(size_t)255;
    return p;
  };
  float* h    = (float*)alloc((size_t)NN * FOUT * 4);     // 25.6 MB
  float* as1  = (float*)alloc((size_t)NN * 4 * 4);
  float* ad1  = (float*)alloc((size_t)NN * 4 * 4);
  int*   deg  = (int*)alloc((size_t)NN * 4);
  int*   offs = (int*)alloc(((size_t)NN + 1) * 4);
  int*   cur  = (int*)alloc((size_t)NN * 4);
  int*   csr  = (int*)alloc((size_t)(EE + NN) * 4);       // 6.6 MB
  float* h2   = (float*)alloc((size_t)NN * 2 * 4);
  float* as2  = (float*)alloc((size_t)NN * 4);
  float* ad2  = (float*)alloc((size_t)NN * 4);
  (void)ws_size; (void)in_sizes; (void)n_in; (void)out_size;

  k_proj   <<<(NN + 63) / 64, 256, 0, stream>>>(x, W1, asw1, adw1, h, as1, ad1);
  k_init   <<<(NN + 255) / 256, 256, 0, stream>>>(deg);
  k_hist   <<<(EE + 255) / 256, 256, 0, stream>>>(ei, deg);
  k_scan   <<<1, 1024, 0, stream>>>(deg, offs, cur);
  k_scatter<<<(EE + NN + 255) / 256, 256, 0, stream>>>(ei, cur, csr);
  k_agg1   <<<(NN + 3) / 4, 256, 0, stream>>>(offs, csr, h, as1, ad1, bias1, gamma, beta,
                                              mean, var, W2, asw2, adw2, h2, as2, ad2);
  k_agg2   <<<(NN + 3) / 4, 256, 0, stream>>>(offs, csr, h2, as2, ad2, bias2, out);
}

// Round 3
// 475.332 us; speedup vs baseline: 1.5111x; 1.2143x over previous
//
#include <hip/hip_runtime.h>
#include <math.h>

#define NN 50000
#define EE 1600000
#define FIN 128
#define FOUT 128   // HEADS*HID
#define NEG 0.2f
#define BNEPS 1e-5f

// float -> bf16 (round-to-nearest-even), branch-free
static __device__ __forceinline__ unsigned short f2bf(float f) {
  unsigned int u = __float_as_uint(f);
  u += 0x7fffu + ((u >> 16) & 1u);
  return (unsigned short)(u >> 16);
}

// ---------------- conv1 projection + attention logits (register-tiled GEMM) ----------------
// Block: 64 nodes x 128 channels. 256 threads, each computes 4 nodes x 8 channels.
#define XS_STRIDE 132
__global__ __launch_bounds__(256) void k_proj(const float* __restrict__ x,
    const float* __restrict__ W1, const float* __restrict__ asw, const float* __restrict__ adw,
    unsigned short* __restrict__ h, float* __restrict__ as1, float* __restrict__ ad1) {
  __shared__ float xs[64 * XS_STRIDE];
  int t = threadIdx.x;
  int nb = blockIdx.x * 64;

  #pragma unroll
  for (int j = 0; j < 8; ++j) {
    int idx = t + 256 * j;
    int r = idx >> 5;
    int c4 = idx & 31;
    int n = nb + r; if (n >= NN) n = NN - 1;
    float4 v = *(const float4*)(x + (size_t)n * FIN + c4 * 4);
    *(float4*)(&xs[r * XS_STRIDE + c4 * 4]) = v;
  }
  __syncthreads();

  int cg = t & 15;        // channel group -> channels cg*8 .. cg*8+7
  int ng = t >> 4;        // node group   -> nodes ng*4 .. ng*4+3
  int c0 = cg * 8;

  float acc[4][8];
  #pragma unroll
  for (int i = 0; i < 4; ++i)
    #pragma unroll
    for (int j = 0; j < 8; ++j) acc[i][j] = 0.f;

  for (int k0 = 0; k0 < FIN; k0 += 4) {
    float xr[4][4];
    #pragma unroll
    for (int i = 0; i < 4; ++i)
      *(float4*)xr[i] = *(const float4*)&xs[(ng * 4 + i) * XS_STRIDE + k0];
    #pragma unroll
    for (int kk = 0; kk < 4; ++kk) {
      float4 w0 = *(const float4*)(W1 + (k0 + kk) * FOUT + c0);
      float4 w1 = *(const float4*)(W1 + (k0 + kk) * FOUT + c0 + 4);
      float wv[8] = {w0.x, w0.y, w0.z, w0.w, w1.x, w1.y, w1.z, w1.w};
      #pragma unroll
      for (int i = 0; i < 4; ++i) {
        float xv = xr[i][kk];
        #pragma unroll
        for (int j = 0; j < 8; ++j) acc[i][j] = fmaf(xv, wv[j], acc[i][j]);
      }
    }
  }

  int head = cg >> 2;
  float vs[4], vd[4];
  #pragma unroll
  for (int i = 0; i < 4; ++i) {
    int n = nb + ng * 4 + i;
    float s = 0.f, d = 0.f;
    #pragma unroll
    for (int j = 0; j < 8; ++j) {
      s = fmaf(acc[i][j], asw[c0 + j], s);
      d = fmaf(acc[i][j], adw[c0 + j], d);
    }
    vs[i] = s; vd[i] = d;
    if (n < NN) {
      // pack 8 channels -> 8 bf16 -> one uint4 store (16B aligned: c0 % 8 == 0)
      uint4 pk;
      pk.x = (unsigned)f2bf(acc[i][0]) | ((unsigned)f2bf(acc[i][1]) << 16);
      pk.y = (unsigned)f2bf(acc[i][2]) | ((unsigned)f2bf(acc[i][3]) << 16);
      pk.z = (unsigned)f2bf(acc[i][4]) | ((unsigned)f2bf(acc[i][5]) << 16);
      pk.w = (unsigned)f2bf(acc[i][6]) | ((unsigned)f2bf(acc[i][7]) << 16);
      *(uint4*)(h + (size_t)n * FOUT + c0) = pk;
    }
  }
  #pragma unroll
  for (int i = 0; i < 4; ++i) {
    vs[i] += __shfl_xor(vs[i], 1, 64); vs[i] += __shfl_xor(vs[i], 2, 64);
    vd[i] += __shfl_xor(vd[i], 1, 64); vd[i] += __shfl_xor(vd[i], 2, 64);
  }
  if ((cg & 3) == 0) {
    #pragma unroll
    for (int i = 0; i < 4; ++i) {
      int n = nb + ng * 4 + i;
      if (n < NN) { as1[n * 4 + head] = vs[i]; ad1[n * 4 + head] = vd[i]; }
    }
  }
}

// ---------------- CSR build (by dst) ----------------
__global__ __launch_bounds__(256) void k_init(int* __restrict__ deg) {
  int i = blockIdx.x * 256 + threadIdx.x;
  if (i < NN) deg[i] = 1;   // self loop
}

__global__ __launch_bounds__(256) void k_hist(const int* __restrict__ ei, int* __restrict__ deg) {
  int i = blockIdx.x * 256 + threadIdx.x;
  if (i < EE) atomicAdd(&deg[ei[EE + i]], 1);
}

__global__ __launch_bounds__(1024) void k_scan(const int* __restrict__ deg,
    int* __restrict__ offs, int* __restrict__ cur) {
  __shared__ int sums[1024];
  int t = threadIdx.x;
  const int CH = (NN + 1023) / 1024;  // 49
  int base = t * CH;
  int s = 0;
  for (int i = 0; i < CH; ++i) { int idx = base + i; if (idx < NN) s += deg[idx]; }
  sums[t] = s; __syncthreads();
  for (int off = 1; off < 1024; off <<= 1) {
    int v = (t >= off) ? sums[t - off] : 0;
    __syncthreads();
    sums[t] += v;
    __syncthreads();
  }
  int run = (t == 0) ? 0 : sums[t - 1];
  for (int i = 0; i < CH; ++i) {
    int idx = base + i;
    if (idx < NN) { offs[idx] = run; cur[idx] = run; run += deg[idx]; }
  }
  if (t == 1023) offs[NN] = sums[1023];
}

__global__ __launch_bounds__(256) void k_scatter(const int* __restrict__ ei,
    int* __restrict__ cur, int* __restrict__ csr) {
  int i = blockIdx.x * 256 + threadIdx.x;
  if (i >= EE + NN) return;
  int s, d;
  if (i < EE) { s = ei[i]; d = ei[EE + i]; }
  else        { s = d = i - EE; }
  int p = atomicAdd(&cur[d], 1);
  csr[p] = s;
}

// ---------------- conv1 aggregation (no-max softmax) + BN + leaky + conv2 projection ----------------
// One wave per dst node; lane owns channels {2*lane, 2*lane+1} (same head: lane>>4).
__global__ __launch_bounds__(256) void k_agg1(
    const int* __restrict__ offs, const int* __restrict__ csr,
    const unsigned short* __restrict__ h, const float* __restrict__ as1, const float* __restrict__ ad1,
    const float* __restrict__ bias1, const float* __restrict__ gamma, const float* __restrict__ beta,
    const float* __restrict__ mean, const float* __restrict__ var,
    const float* __restrict__ W2, const float* __restrict__ asw2, const float* __restrict__ adw2,
    float* __restrict__ h2, float* __restrict__ as2, float* __restrict__ ad2) {
  int wid = threadIdx.x >> 6;
  int lane = threadIdx.x & 63;
  int n = blockIdx.x * 4 + wid;
  if (n >= NN) return;
  int r0 = offs[n], r1 = offs[n + 1];
  int hh = lane >> 4;                       // head of this lane's channel pair
  float ad = ad1[n * 4 + hh];
  const unsigned int* hp = (const unsigned int*)h;   // u32 = 2 bf16 channels

  float acc0 = 0.f, acc1 = 0.f, den = 0.f;
  #pragma unroll 2
  for (int i = r0; i < r1; ++i) {
    int s = csr[i];
    float e = as1[s * 4 + hh] + ad;
    e = e > 0.f ? e : NEG * e;
    float ex = __expf(e);                   // no max subtraction: |e| is O(1), safe in fp32
    den += ex;
    unsigned int pv = hp[(size_t)s * 64 + lane];
    float v0 = __uint_as_float(pv << 16);
    float v1 = __uint_as_float(pv & 0xffff0000u);
    acc0 = fmaf(ex, v0, acc0);
    acc1 = fmaf(ex, v1, acc1);
  }

  int c0 = lane * 2, c1 = lane * 2 + 1;
  float inv = 1.f / den;
  float o0 = acc0 * inv + bias1[c0];
  float o1 = acc1 * inv + bias1[c1];
  o0 = gamma[c0] * (o0 - mean[c0]) * rsqrtf(var[c0] + BNEPS) + beta[c0];
  o1 = gamma[c1] * (o1 - mean[c1]) * rsqrtf(var[c1] + BNEPS) + beta[c1];
  o0 = o0 > 0.f ? o0 : NEG * o0;
  o1 = o1 > 0.f ? o1 : NEG * o1;

  // conv2 projection: p = h1b @ W2 (reduce 128 features across the wave)
  float p0 = o0 * W2[c0 * 2 + 0] + o1 * W2[c1 * 2 + 0];
  float p1 = o0 * W2[c0 * 2 + 1] + o1 * W2[c1 * 2 + 1];
  #pragma unroll
  for (int mm = 32; mm >= 1; mm >>= 1) {
    p0 += __shfl_xor(p0, mm, 64);
    p1 += __shfl_xor(p1, mm, 64);
  }
  if (lane == 0) {
    h2[n * 2 + 0] = p0;
    h2[n * 2 + 1] = p1;
    as2[n] = p0 * asw2[0] + p1 * asw2[1];
    ad2[n] = p0 * adw2[0] + p1 * adw2[1];
  }
}

// ---------------- conv2 aggregation (no-max softmax) + bias + log_softmax ----------------
__global__ __launch_bounds__(256) void k_agg2(
    const int* __restrict__ offs, const int* __restrict__ csr,
    const float* __restrict__ h2, const float* __restrict__ as2, const float* __restrict__ ad2,
    const float* __restrict__ bias2, float* __restrict__ out) {
  int wid = threadIdx.x >> 6;
  int lane = threadIdx.x & 63;
  int n = blockIdx.x * 4 + wid;
  if (n >= NN) return;
  int r0 = offs[n], r1 = offs[n + 1];
  float ad = ad2[n];

  float den = 0.f, a0 = 0.f, a1 = 0.f;
  for (int i = r0 + lane; i < r1; i += 64) {
    int s = csr[i];
    float e = as2[s] + ad; e = e > 0.f ? e : NEG * e;
    float ex = __expf(e);                   // no max subtraction: |e| tiny
    float2 hv = *(const float2*)(h2 + s * 2);
    den += ex;
    a0 = fmaf(ex, hv.x, a0);
    a1 = fmaf(ex, hv.y, a1);
  }
  #pragma unroll
  for (int mm = 32; mm >= 1; mm >>= 1) {
    den += __shfl_xor(den, mm, 64);
    a0  += __shfl_xor(a0, mm, 64);
    a1  += __shfl_xor(a1, mm, 64);
  }
  if (lane == 0) {
    float o0 = a0 / den + bias2[0];
    float o1 = a1 / den + bias2[1];
    float mx = fmaxf(o0, o1);
    float lse = mx + logf(__expf(o0 - mx) + __expf(o1 - mx));
    out[n * 2 + 0] = o0 - lse;
    out[n * 2 + 1] = o1 - lse;
  }
}

extern "C" void kernel_launch(void* const* d_in, const int* in_sizes, int n_in,
                              void* d_out, int out_size, void* d_ws, size_t ws_size,
                              hipStream_t stream) {
  const float* x     = (const float*)d_in[0];
  const int*   ei    = (const int*)d_in[1];
  const float* W1    = (const float*)d_in[2];
  const float* asw1  = (const float*)d_in[3];
  const float* adw1  = (const float*)d_in[4];
  const float* bias1 = (const float*)d_in[5];
  const float* gamma = (const float*)d_in[6];
  const float* beta  = (const float*)d_in[7];
  const float* mean  = (const float*)d_in[8];
  const float* var   = (const float*)d_in[9];
  const float* W2    = (const float*)d_in[10];
  const float* asw2  = (const float*)d_in[11];
  const float* adw2  = (const float*)d_in[12];
  const float* bias2 = (const float*)d_in[13];
  float* out = (float*)d_out;

  char* ws = (char*)d_ws;
  size_t off = 0;
  auto alloc = [&](size_t bytes) {
    void* p = ws + off;
    off += (bytes + 255) & ~(size_t)255;
    return p;
  };
  unsigned short* h = (unsigned short*)alloc((size_t)NN * FOUT * 2);  // 12.8 MB bf16
  float* as1  = (float*)alloc((size_t)NN * 4 * 4);
  float* ad1  = (float*)alloc((size_t)NN * 4 * 4);
  int*   deg  = (int*)alloc((size_t)NN * 4);
  int*   offs = (int*)alloc(((size_t)NN + 1) * 4);
  int*   cur  = (int*)alloc((size_t)NN * 4);
  int*   csr  = (int*)alloc((size_t)(EE + NN) * 4);
  float* h2   = (float*)alloc((size_t)NN * 2 * 4);
  float* as2  = (float*)alloc((size_t)NN * 4);
  float* ad2  = (float*)alloc((size_t)NN * 4);
  (void)ws_size; (void)in_sizes; (void)n_in; (void)out_size;

  k_proj   <<<(NN + 63) / 64, 256, 0, stream>>>(x, W1, asw1, adw1, h, as1, ad1);
  k_init   <<<(NN + 255) / 256, 256, 0, stream>>>(deg);
  k_hist   <<<(EE + 255) / 256, 256, 0, stream>>>(ei, deg);
  k_scan   <<<1, 1024, 0, stream>>>(deg, offs, cur);
  k_scatter<<<(EE + NN + 255) / 256, 256, 0, stream>>>(ei, cur, csr);
  k_agg1   <<<(NN + 3) / 4, 256, 0, stream>>>(offs, csr, h, as1, ad1, bias1, gamma, beta,
                                              mean, var, W2, asw2, adw2, h2, as2, ad2);
  k_agg2   <<<(NN + 3) / 4, 256, 0, stream>>>(offs, csr, h2, as2, ad2, bias2, out);
}

// Round 4
// 427.811 us; speedup vs baseline: 1.6790x; 1.1111x over previous
//
#include <hip/hip_runtime.h>
#include <math.h>

#define NN 50000
#define EE 1600000
#define FIN 128
#define FOUT 128   // HEADS*HID
#define NEG 0.2f
#define BNEPS 1e-5f

#define NPART 8
#define PSZ (NN / NPART)   // 6250 (divides exactly)

// float -> bf16 (round-to-nearest-even), branch-free
static __device__ __forceinline__ unsigned short f2bf(float f) {
  unsigned int u = __float_as_uint(f);
  u += 0x7fffu + ((u >> 16) & 1u);
  return (unsigned short)(u >> 16);
}

// ---------------- conv1 projection + attention logits (register-tiled GEMM) ----------------
#define XS_STRIDE 132
__global__ __launch_bounds__(256) void k_proj(const float* __restrict__ x,
    const float* __restrict__ W1, const float* __restrict__ asw, const float* __restrict__ adw,
    unsigned short* __restrict__ h, float* __restrict__ as1, float* __restrict__ ad1) {
  __shared__ float xs[64 * XS_STRIDE];
  int t = threadIdx.x;
  int nb = blockIdx.x * 64;

  #pragma unroll
  for (int j = 0; j < 8; ++j) {
    int idx = t + 256 * j;
    int r = idx >> 5;
    int c4 = idx & 31;
    int n = nb + r; if (n >= NN) n = NN - 1;
    float4 v = *(const float4*)(x + (size_t)n * FIN + c4 * 4);
    *(float4*)(&xs[r * XS_STRIDE + c4 * 4]) = v;
  }
  __syncthreads();

  int cg = t & 15;
  int ng = t >> 4;
  int c0 = cg * 8;

  float acc[4][8];
  #pragma unroll
  for (int i = 0; i < 4; ++i)
    #pragma unroll
    for (int j = 0; j < 8; ++j) acc[i][j] = 0.f;

  for (int k0 = 0; k0 < FIN; k0 += 4) {
    float xr[4][4];
    #pragma unroll
    for (int i = 0; i < 4; ++i)
      *(float4*)xr[i] = *(const float4*)&xs[(ng * 4 + i) * XS_STRIDE + k0];
    #pragma unroll
    for (int kk = 0; kk < 4; ++kk) {
      float4 w0 = *(const float4*)(W1 + (k0 + kk) * FOUT + c0);
      float4 w1 = *(const float4*)(W1 + (k0 + kk) * FOUT + c0 + 4);
      float wv[8] = {w0.x, w0.y, w0.z, w0.w, w1.x, w1.y, w1.z, w1.w};
      #pragma unroll
      for (int i = 0; i < 4; ++i) {
        float xv = xr[i][kk];
        #pragma unroll
        for (int j = 0; j < 8; ++j) acc[i][j] = fmaf(xv, wv[j], acc[i][j]);
      }
    }
  }

  int head = cg >> 2;
  float vs[4], vd[4];
  #pragma unroll
  for (int i = 0; i < 4; ++i) {
    int n = nb + ng * 4 + i;
    float s = 0.f, d = 0.f;
    #pragma unroll
    for (int j = 0; j < 8; ++j) {
      s = fmaf(acc[i][j], asw[c0 + j], s);
      d = fmaf(acc[i][j], adw[c0 + j], d);
    }
    vs[i] = s; vd[i] = d;
    if (n < NN) {
      uint4 pk;
      pk.x = (unsigned)f2bf(acc[i][0]) | ((unsigned)f2bf(acc[i][1]) << 16);
      pk.y = (unsigned)f2bf(acc[i][2]) | ((unsigned)f2bf(acc[i][3]) << 16);
      pk.z = (unsigned)f2bf(acc[i][4]) | ((unsigned)f2bf(acc[i][5]) << 16);
      pk.w = (unsigned)f2bf(acc[i][6]) | ((unsigned)f2bf(acc[i][7]) << 16);
      *(uint4*)(h + (size_t)n * FOUT + c0) = pk;
    }
  }
  #pragma unroll
  for (int i = 0; i < 4; ++i) {
    vs[i] += __shfl_xor(vs[i], 1, 64); vs[i] += __shfl_xor(vs[i], 2, 64);
    vd[i] += __shfl_xor(vd[i], 1, 64); vd[i] += __shfl_xor(vd[i], 2, 64);
  }
  if ((cg & 3) == 0) {
    #pragma unroll
    for (int i = 0; i < 4; ++i) {
      int n = nb + ng * 4 + i;
      if (n < NN) { as1[n * 4 + head] = vs[i]; ad1[n * 4 + head] = vd[i]; }
    }
  }
}

// ---------------- CSR build (by dst) ----------------
__global__ __launch_bounds__(256) void k_init(int* __restrict__ deg) {
  int i = blockIdx.x * 256 + threadIdx.x;
  if (i < NN) deg[i] = 1;   // self loop
}

__global__ __launch_bounds__(256) void k_hist(const int* __restrict__ ei, int* __restrict__ deg) {
  int i = blockIdx.x * 256 + threadIdx.x;
  if (i < EE) atomicAdd(&deg[ei[EE + i]], 1);
}

__global__ __launch_bounds__(1024) void k_scan(const int* __restrict__ deg,
    int* __restrict__ offs, int* __restrict__ cur) {
  __shared__ int sums[1024];
  int t = threadIdx.x;
  const int CH = (NN + 1023) / 1024;  // 49
  int base = t * CH;
  int s = 0;
  for (int i = 0; i < CH; ++i) { int idx = base + i; if (idx < NN) s += deg[idx]; }
  sums[t] = s; __syncthreads();
  for (int off = 1; off < 1024; off <<= 1) {
    int v = (t >= off) ? sums[t - off] : 0;
    __syncthreads();
    sums[t] += v;
    __syncthreads();
  }
  int run = (t == 0) ? 0 : sums[t - 1];
  for (int i = 0; i < CH; ++i) {
    int idx = base + i;
    if (idx < NN) { offs[idx] = run; cur[idx] = run; run += deg[idx]; }
  }
  if (t == 1023) offs[NN] = sums[1023];
}

// dst-range-partitioned scatter: partition = blockIdx & 7 -> co-resident on one XCD
// (round-robin dispatch). Each partition's csr slice (~825 KB) stays in that XCD's L2,
// so the 16 dword writes per line combine before writeback. Self-loops folded in.
__global__ __launch_bounds__(256) void k_scatter(const int* __restrict__ ei,
    int* __restrict__ cur, int* __restrict__ csr) {
  int part = blockIdx.x & (NPART - 1);
  int blk  = blockIdx.x >> 3;
  int nblk = gridDim.x >> 3;
  int lo = part * PSZ, hi = lo + PSZ;

  for (int i = blk * 256 + threadIdx.x; i < EE; i += nblk * 256) {
    int d = ei[EE + i];
    if (d >= lo && d < hi) {
      int s = ei[i];
      int p = atomicAdd(&cur[d], 1);
      csr[p] = s;
    }
  }
  // self loops for this partition's dst range
  for (int n = lo + blk * 256 + threadIdx.x; n < hi; n += nblk * 256) {
    int p = atomicAdd(&cur[n], 1);
    csr[p] = n;
  }
}

// ---------------- conv1 aggregation (no-max softmax) + BN + leaky + conv2 projection ----------------
__global__ __launch_bounds__(256) void k_agg1(
    const int* __restrict__ offs, const int* __restrict__ csr,
    const unsigned short* __restrict__ h, const float* __restrict__ as1, const float* __restrict__ ad1,
    const float* __restrict__ bias1, const float* __restrict__ gamma, const float* __restrict__ beta,
    const float* __restrict__ mean, const float* __restrict__ var,
    const float* __restrict__ W2, const float* __restrict__ asw2, const float* __restrict__ adw2,
    float* __restrict__ h2, float* __restrict__ as2, float* __restrict__ ad2) {
  int wid = threadIdx.x >> 6;
  int lane = threadIdx.x & 63;
  int n = blockIdx.x * 4 + wid;
  if (n >= NN) return;
  int r0 = offs[n], r1 = offs[n + 1];
  int hh = lane >> 4;
  float ad = ad1[n * 4 + hh];
  const unsigned int* hp = (const unsigned int*)h;

  float acc0 = 0.f, acc1 = 0.f, den = 0.f;
  #pragma unroll 2
  for (int i = r0; i < r1; ++i) {
    int s = csr[i];
    float e = as1[s * 4 + hh] + ad;
    e = e > 0.f ? e : NEG * e;
    float ex = __expf(e);
    den += ex;
    unsigned int pv = hp[(size_t)s * 64 + lane];
    float v0 = __uint_as_float(pv << 16);
    float v1 = __uint_as_float(pv & 0xffff0000u);
    acc0 = fmaf(ex, v0, acc0);
    acc1 = fmaf(ex, v1, acc1);
  }

  int c0 = lane * 2, c1 = lane * 2 + 1;
  float inv = 1.f / den;
  float o0 = acc0 * inv + bias1[c0];
  float o1 = acc1 * inv + bias1[c1];
  o0 = gamma[c0] * (o0 - mean[c0]) * rsqrtf(var[c0] + BNEPS) + beta[c0];
  o1 = gamma[c1] * (o1 - mean[c1]) * rsqrtf(var[c1] + BNEPS) + beta[c1];
  o0 = o0 > 0.f ? o0 : NEG * o0;
  o1 = o1 > 0.f ? o1 : NEG * o1;

  float p0 = o0 * W2[c0 * 2 + 0] + o1 * W2[c1 * 2 + 0];
  float p1 = o0 * W2[c0 * 2 + 1] + o1 * W2[c1 * 2 + 1];
  #pragma unroll
  for (int mm = 32; mm >= 1; mm >>= 1) {
    p0 += __shfl_xor(p0, mm, 64);
    p1 += __shfl_xor(p1, mm, 64);
  }
  if (lane == 0) {
    h2[n * 2 + 0] = p0;
    h2[n * 2 + 1] = p1;
    as2[n] = p0 * asw2[0] + p1 * asw2[1];
    ad2[n] = p0 * adw2[0] + p1 * adw2[1];
  }
}

// ---------------- conv2 aggregation (no-max softmax) + bias + log_softmax ----------------
__global__ __launch_bounds__(256) void k_agg2(
    const int* __restrict__ offs, const int* __restrict__ csr,
    const float* __restrict__ h2, const float* __restrict__ as2, const float* __restrict__ ad2,
    const float* __restrict__ bias2, float* __restrict__ out) {
  int wid = threadIdx.x >> 6;
  int lane = threadIdx.x & 63;
  int n = blockIdx.x * 4 + wid;
  if (n >= NN) return;
  int r0 = offs[n], r1 = offs[n + 1];
  float ad = ad2[n];

  float den = 0.f, a0 = 0.f, a1 = 0.f;
  for (int i = r0 + lane; i < r1; i += 64) {
    int s = csr[i];
    float e = as2[s] + ad; e = e > 0.f ? e : NEG * e;
    float ex = __expf(e);
    float2 hv = *(const float2*)(h2 + s * 2);
    den += ex;
    a0 = fmaf(ex, hv.x, a0);
    a1 = fmaf(ex, hv.y, a1);
  }
  #pragma unroll
  for (int mm = 32; mm >= 1; mm >>= 1) {
    den += __shfl_xor(den, mm, 64);
    a0  += __shfl_xor(a0, mm, 64);
    a1  += __shfl_xor(a1, mm, 64);
  }
  if (lane == 0) {
    float o0 = a0 / den + bias2[0];
    float o1 = a1 / den + bias2[1];
    float mx = fmaxf(o0, o1);
    float lse = mx + logf(__expf(o0 - mx) + __expf(o1 - mx));
    out[n * 2 + 0] = o0 - lse;
    out[n * 2 + 1] = o1 - lse;
  }
}

extern "C" void kernel_launch(void* const* d_in, const int* in_sizes, int n_in,
                              void* d_out, int out_size, void* d_ws, size_t ws_size,
                              hipStream_t stream) {
  const float* x     = (const float*)d_in[0];
  const int*   ei    = (const int*)d_in[1];
  const float* W1    = (const float*)d_in[2];
  const float* asw1  = (const float*)d_in[3];
  const float* adw1  = (const float*)d_in[4];
  const float* bias1 = (const float*)d_in[5];
  const float* gamma = (const float*)d_in[6];
  const float* beta  = (const float*)d_in[7];
  const float* mean  = (const float*)d_in[8];
  const float* var   = (const float*)d_in[9];
  const float* W2    = (const float*)d_in[10];
  const float* asw2  = (const float*)d_in[11];
  const float* adw2  = (const float*)d_in[12];
  const float* bias2 = (const float*)d_in[13];
  float* out = (float*)d_out;

  char* ws = (char*)d_ws;
  size_t off = 0;
  auto alloc = [&](size_t bytes) {
    void* p = ws + off;
    off += (bytes + 255) & ~(size_t)255;
    return p;
  };
  unsigned short* h = (unsigned short*)alloc((size_t)NN * FOUT * 2);  // 12.8 MB bf16
  float* as1  = (float*)alloc((size_t)NN * 4 * 4);
  float* ad1  = (float*)alloc((size_t)NN * 4 * 4);
  int*   deg  = (int*)alloc((size_t)NN * 4);
  int*   offs = (int*)alloc(((size_t)NN + 1) * 4);
  int*   cur  = (int*)alloc((size_t)NN * 4);
  int*   csr  = (int*)alloc((size_t)(EE + NN) * 4);
  float* h2   = (float*)alloc((size_t)NN * 2 * 4);
  float* as2  = (float*)alloc((size_t)NN * 4);
  float* ad2  = (float*)alloc((size_t)NN * 4);
  (void)ws_size; (void)in_sizes; (void)n_in; (void)out_size;

  k_proj   <<<(NN + 63) / 64, 256, 0, stream>>>(x, W1, asw1, adw1, h, as1, ad1);
  k_init   <<<(NN + 255) / 256, 256, 0, stream>>>(deg);
  k_hist   <<<(EE + 255) / 256, 256, 0, stream>>>(ei, deg);
  k_scan   <<<1, 1024, 0, stream>>>(deg, offs, cur);
  k_scatter<<<2048, 256, 0, stream>>>(ei, cur, csr);   // 8 partitions x 256 blocks
  k_agg1   <<<(NN + 3) / 4, 256, 0, stream>>>(offs, csr, h, as1, ad1, bias1, gamma, beta,
                                              mean, var, W2, asw2, adw2, h2, as2, ad2);
  k_agg2   <<<(NN + 3) / 4, 256, 0, stream>>>(offs, csr, h2, as2, ad2, bias2, out);
}

// Round 5
// 314.047 us; speedup vs baseline: 2.2872x; 1.3623x over previous
//
#include <hip/hip_runtime.h>
#include <math.h>

#define NN 50000
#define EE 1600000
#define FIN 128
#define FOUT 128   // HEADS*HID
#define NEG 0.2f
#define BNEPS 1e-5f

#define NPART 8
#define PSZ (NN / NPART)   // 6250

#define SCB 49             // scan blocks (49*1024 >= 50000)

// float -> bf16 (round-to-nearest-even), branch-free
static __device__ __forceinline__ unsigned short f2bf(float f) {
  unsigned int u = __float_as_uint(f);
  u += 0x7fffu + ((u >> 16) & 1u);
  return (unsigned short)(u >> 16);
}

// ---------------- conv1 projection + attention logits (register-tiled GEMM) ----------------
#define XS_STRIDE 132
__global__ __launch_bounds__(256) void k_proj(const float* __restrict__ x,
    const float* __restrict__ W1, const float* __restrict__ asw, const float* __restrict__ adw,
    unsigned short* __restrict__ h, float* __restrict__ as1, float* __restrict__ ad1) {
  __shared__ float xs[64 * XS_STRIDE];
  int t = threadIdx.x;
  int nb = blockIdx.x * 64;

  #pragma unroll
  for (int j = 0; j < 8; ++j) {
    int idx = t + 256 * j;
    int r = idx >> 5;
    int c4 = idx & 31;
    int n = nb + r; if (n >= NN) n = NN - 1;
    float4 v = *(const float4*)(x + (size_t)n * FIN + c4 * 4);
    *(float4*)(&xs[r * XS_STRIDE + c4 * 4]) = v;
  }
  __syncthreads();

  int cg = t & 15;
  int ng = t >> 4;
  int c0 = cg * 8;

  float acc[4][8];
  #pragma unroll
  for (int i = 0; i < 4; ++i)
    #pragma unroll
    for (int j = 0; j < 8; ++j) acc[i][j] = 0.f;

  for (int k0 = 0; k0 < FIN; k0 += 4) {
    float xr[4][4];
    #pragma unroll
    for (int i = 0; i < 4; ++i)
      *(float4*)xr[i] = *(const float4*)&xs[(ng * 4 + i) * XS_STRIDE + k0];
    #pragma unroll
    for (int kk = 0; kk < 4; ++kk) {
      float4 w0 = *(const float4*)(W1 + (k0 + kk) * FOUT + c0);
      float4 w1 = *(const float4*)(W1 + (k0 + kk) * FOUT + c0 + 4);
      float wv[8] = {w0.x, w0.y, w0.z, w0.w, w1.x, w1.y, w1.z, w1.w};
      #pragma unroll
      for (int i = 0; i < 4; ++i) {
        float xv = xr[i][kk];
        #pragma unroll
        for (int j = 0; j < 8; ++j) acc[i][j] = fmaf(xv, wv[j], acc[i][j]);
      }
    }
  }

  int head = cg >> 2;
  float vs[4], vd[4];
  #pragma unroll
  for (int i = 0; i < 4; ++i) {
    int n = nb + ng * 4 + i;
    float s = 0.f, d = 0.f;
    #pragma unroll
    for (int j = 0; j < 8; ++j) {
      s = fmaf(acc[i][j], asw[c0 + j], s);
      d = fmaf(acc[i][j], adw[c0 + j], d);
    }
    vs[i] = s; vd[i] = d;
    if (n < NN) {
      uint4 pk;
      pk.x = (unsigned)f2bf(acc[i][0]) | ((unsigned)f2bf(acc[i][1]) << 16);
      pk.y = (unsigned)f2bf(acc[i][2]) | ((unsigned)f2bf(acc[i][3]) << 16);
      pk.z = (unsigned)f2bf(acc[i][4]) | ((unsigned)f2bf(acc[i][5]) << 16);
      pk.w = (unsigned)f2bf(acc[i][6]) | ((unsigned)f2bf(acc[i][7]) << 16);
      *(uint4*)(h + (size_t)n * FOUT + c0) = pk;
    }
  }
  #pragma unroll
  for (int i = 0; i < 4; ++i) {
    vs[i] += __shfl_xor(vs[i], 1, 64); vs[i] += __shfl_xor(vs[i], 2, 64);
    vd[i] += __shfl_xor(vd[i], 1, 64); vd[i] += __shfl_xor(vd[i], 2, 64);
  }
  if ((cg & 3) == 0) {
    #pragma unroll
    for (int i = 0; i < 4; ++i) {
      int n = nb + ng * 4 + i;
      if (n < NN) { as1[n * 4 + head] = vs[i]; ad1[n * 4 + head] = vd[i]; }
    }
  }
}

// ---------------- CSR build (by dst) ----------------
__global__ __launch_bounds__(256) void k_init(int* __restrict__ deg) {
  int i = blockIdx.x * 256 + threadIdx.x;
  if (i < NN) deg[i] = 1;   // self loop
}

__global__ __launch_bounds__(256) void k_hist(const int* __restrict__ ei, int* __restrict__ deg) {
  int i = blockIdx.x * 256 + threadIdx.x;
  if (i < EE) atomicAdd(&deg[ei[EE + i]], 1);
}

// hierarchical scan, level 1: per-block Hillis-Steele over 1024 nodes.
// writes within-block EXCLUSIVE prefix -> cur (temp), block total -> bsum.
__global__ __launch_bounds__(1024) void k_scanA(const int* __restrict__ deg,
    int* __restrict__ cur, int* __restrict__ bsum) {
  __shared__ int sums[1024];
  int t = threadIdx.x;
  int idx = blockIdx.x * 1024 + t;
  int v = (idx < NN) ? deg[idx] : 0;
  sums[t] = v; __syncthreads();
  #pragma unroll
  for (int off = 1; off < 1024; off <<= 1) {
    int u = (t >= off) ? sums[t - off] : 0;
    __syncthreads();
    sums[t] += u;
    __syncthreads();
  }
  if (idx < NN) cur[idx] = sums[t] - v;        // exclusive within block
  if (t == 1023) bsum[blockIdx.x] = sums[1023];
}

// level 2: add block base, write offs + cur. Each thread redundantly sums bsum[0..b-1].
__global__ __launch_bounds__(1024) void k_scanB(const int* __restrict__ bsum,
    int* __restrict__ offs, int* __restrict__ cur) {
  int b = blockIdx.x;
  int t = threadIdx.x;
  int base = 0;
  for (int i = 0; i < SCB; ++i) base += (i < b) ? bsum[i] : 0;
  int idx = b * 1024 + t;
  if (idx < NN) {
    int v = cur[idx] + base;
    offs[idx] = v;
    cur[idx] = v;
  }
  if (b == SCB - 1 && t == 0) {
    int total = base;
    for (int i = b; i < SCB; ++i) total += bsum[i];
    offs[NN] = total;   // = EE + NN
  }
}

// dst-range-partitioned scatter (XCD L2 locality)
__global__ __launch_bounds__(256) void k_scatter(const int* __restrict__ ei,
    int* __restrict__ cur, int* __restrict__ csr) {
  int part = blockIdx.x & (NPART - 1);
  int blk  = blockIdx.x >> 3;
  int nblk = gridDim.x >> 3;
  int lo = part * PSZ, hi = lo + PSZ;

  for (int i = blk * 256 + threadIdx.x; i < EE; i += nblk * 256) {
    int d = ei[EE + i];
    if (d >= lo && d < hi) {
      int s = ei[i];
      int p = atomicAdd(&cur[d], 1);
      csr[p] = s;
    }
  }
  for (int n = lo + blk * 256 + threadIdx.x; n < hi; n += nblk * 256) {
    int p = atomicAdd(&cur[n], 1);
    csr[p] = n;
  }
}

// ---------------- conv1 aggregation (no-max softmax) + BN + leaky + conv2 projection ----------------
__global__ __launch_bounds__(256) void k_agg1(
    const int* __restrict__ offs, const int* __restrict__ csr,
    const unsigned short* __restrict__ h, const float* __restrict__ as1, const float* __restrict__ ad1,
    const float* __restrict__ bias1, const float* __restrict__ gamma, const float* __restrict__ beta,
    const float* __restrict__ mean, const float* __restrict__ var,
    const float* __restrict__ W2, const float* __restrict__ asw2, const float* __restrict__ adw2,
    float* __restrict__ h2, float* __restrict__ as2, float* __restrict__ ad2) {
  int wid = threadIdx.x >> 6;
  int lane = threadIdx.x & 63;
  int n = blockIdx.x * 4 + wid;
  if (n >= NN) return;
  int r0 = offs[n], r1 = offs[n + 1];
  int hh = lane >> 4;
  float ad = ad1[n * 4 + hh];
  const unsigned int* hp = (const unsigned int*)h;

  float acc0 = 0.f, acc1 = 0.f, den = 0.f;
  #pragma unroll 2
  for (int i = r0; i < r1; ++i) {
    int s = csr[i];
    float e = as1[s * 4 + hh] + ad;
    e = e > 0.f ? e : NEG * e;
    float ex = __expf(e);
    den += ex;
    unsigned int pv = hp[(size_t)s * 64 + lane];
    float v0 = __uint_as_float(pv << 16);
    float v1 = __uint_as_float(pv & 0xffff0000u);
    acc0 = fmaf(ex, v0, acc0);
    acc1 = fmaf(ex, v1, acc1);
  }

  int c0 = lane * 2, c1 = lane * 2 + 1;
  float inv = 1.f / den;
  float o0 = acc0 * inv + bias1[c0];
  float o1 = acc1 * inv + bias1[c1];
  o0 = gamma[c0] * (o0 - mean[c0]) * rsqrtf(var[c0] + BNEPS) + beta[c0];
  o1 = gamma[c1] * (o1 - mean[c1]) * rsqrtf(var[c1] + BNEPS) + beta[c1];
  o0 = o0 > 0.f ? o0 : NEG * o0;
  o1 = o1 > 0.f ? o1 : NEG * o1;

  float p0 = o0 * W2[c0 * 2 + 0] + o1 * W2[c1 * 2 + 0];
  float p1 = o0 * W2[c0 * 2 + 1] + o1 * W2[c1 * 2 + 1];
  #pragma unroll
  for (int mm = 32; mm >= 1; mm >>= 1) {
    p0 += __shfl_xor(p0, mm, 64);
    p1 += __shfl_xor(p1, mm, 64);
  }
  if (lane == 0) {
    h2[n * 2 + 0] = p0;
    h2[n * 2 + 1] = p1;
    as2[n] = p0 * asw2[0] + p1 * asw2[1];
    ad2[n] = p0 * adw2[0] + p1 * adw2[1];
  }
}

// ---------------- conv2 aggregation (no-max softmax) + bias + log_softmax ----------------
__global__ __launch_bounds__(256) void k_agg2(
    const int* __restrict__ offs, const int* __restrict__ csr,
    const float* __restrict__ h2, const float* __restrict__ as2, const float* __restrict__ ad2,
    const float* __restrict__ bias2, float* __restrict__ out) {
  int wid = threadIdx.x >> 6;
  int lane = threadIdx.x & 63;
  int n = blockIdx.x * 4 + wid;
  if (n >= NN) return;
  int r0 = offs[n], r1 = offs[n + 1];
  float ad = ad2[n];

  float den = 0.f, a0 = 0.f, a1 = 0.f;
  for (int i = r0 + lane; i < r1; i += 64) {
    int s = csr[i];
    float e = as2[s] + ad; e = e > 0.f ? e : NEG * e;
    float ex = __expf(e);
    float2 hv = *(const float2*)(h2 + s * 2);
    den += ex;
    a0 = fmaf(ex, hv.x, a0);
    a1 = fmaf(ex, hv.y, a1);
  }
  #pragma unroll
  for (int mm = 32; mm >= 1; mm >>= 1) {
    den += __shfl_xor(den, mm, 64);
    a0  += __shfl_xor(a0, mm, 64);
    a1  += __shfl_xor(a1, mm, 64);
  }
  if (lane == 0) {
    float o0 = a0 / den + bias2[0];
    float o1 = a1 / den + bias2[1];
    float mx = fmaxf(o0, o1);
    float lse = mx + logf(__expf(o0 - mx) + __expf(o1 - mx));
    out[n * 2 + 0] = o0 - lse;
    out[n * 2 + 1] = o1 - lse;
  }
}

extern "C" void kernel_launch(void* const* d_in, const int* in_sizes, int n_in,
                              void* d_out, int out_size, void* d_ws, size_t ws_size,
                              hipStream_t stream) {
  const float* x     = (const float*)d_in[0];
  const int*   ei    = (const int*)d_in[1];
  const float* W1    = (const float*)d_in[2];
  const float* asw1  = (const float*)d_in[3];
  const float* adw1  = (const float*)d_in[4];
  const float* bias1 = (const float*)d_in[5];
  const float* gamma = (const float*)d_in[6];
  const float* beta  = (const float*)d_in[7];
  const float* mean  = (const float*)d_in[8];
  const float* var   = (const float*)d_in[9];
  const float* W2    = (const float*)d_in[10];
  const float* asw2  = (const float*)d_in[11];
  const float* adw2  = (const float*)d_in[12];
  const float* bias2 = (const float*)d_in[13];
  float* out = (float*)d_out;

  char* ws = (char*)d_ws;
  size_t off = 0;
  auto alloc = [&](size_t bytes) {
    void* p = ws + off;
    off += (bytes + 255) & ~(size_t)255;
    return p;
  };
  unsigned short* h = (unsigned short*)alloc((size_t)NN * FOUT * 2);  // 12.8 MB bf16
  float* as1  = (float*)alloc((size_t)NN * 4 * 4);
  float* ad1  = (float*)alloc((size_t)NN * 4 * 4);
  int*   deg  = (int*)alloc((size_t)NN * 4);
  int*   offs = (int*)alloc(((size_t)NN + 1) * 4);
  int*   cur  = (int*)alloc((size_t)NN * 4);
  int*   bsum = (int*)alloc((size_t)SCB * 4);
  int*   csr  = (int*)alloc((size_t)(EE + NN) * 4);
  float* h2   = (float*)alloc((size_t)NN * 2 * 4);
  float* as2  = (float*)alloc((size_t)NN * 4);
  float* ad2  = (float*)alloc((size_t)NN * 4);
  (void)ws_size; (void)in_sizes; (void)n_in; (void)out_size;

  k_proj   <<<(NN + 63) / 64, 256, 0, stream>>>(x, W1, asw1, adw1, h, as1, ad1);
  k_init   <<<(NN + 255) / 256, 256, 0, stream>>>(deg);
  k_hist   <<<(EE + 255) / 256, 256, 0, stream>>>(ei, deg);
  k_scanA  <<<SCB, 1024, 0, stream>>>(deg, cur, bsum);
  k_scanB  <<<SCB, 1024, 0, stream>>>(bsum, offs, cur);
  k_scatter<<<2048, 256, 0, stream>>>(ei, cur, csr);
  k_agg1   <<<(NN + 3) / 4, 256, 0, stream>>>(offs, csr, h, as1, ad1, bias1, gamma, beta,
                                              mean, var, W2, asw2, adw2, h2, as2, ad2);
  k_agg2   <<<(NN + 3) / 4, 256, 0, stream>>>(offs, csr, h2, as2, ad2, bias2, out);
}

// Round 6
// 312.870 us; speedup vs baseline: 2.2958x; 1.0038x over previous
//
#include <hip/hip_runtime.h>
#include <math.h>

#define NN 50000
#define EE 1600000
#define FIN 128
#define FOUT 128   // HEADS*HID
#define NEG 0.2f
#define BNEPS 1e-5f

#define NPART 8
#define PSZ (NN / NPART)   // 6250

#define SCB 49             // scan blocks (49*1024 >= 50000)

// ---------------- conv1 projection + attention logits (register-tiled GEMM) ----------------
// h is stored int8 with per-row scale: h[n][c] ~= q[n][c] * scale[n], q in [-127,127].
#define XS_STRIDE 132
__global__ __launch_bounds__(256) void k_proj(const float* __restrict__ x,
    const float* __restrict__ W1, const float* __restrict__ asw, const float* __restrict__ adw,
    signed char* __restrict__ h8, float* __restrict__ hscale,
    float* __restrict__ as1, float* __restrict__ ad1) {
  __shared__ float xs[64 * XS_STRIDE];
  int t = threadIdx.x;
  int nb = blockIdx.x * 64;

  #pragma unroll
  for (int j = 0; j < 8; ++j) {
    int idx = t + 256 * j;
    int r = idx >> 5;
    int c4 = idx & 31;
    int n = nb + r; if (n >= NN) n = NN - 1;
    float4 v = *(const float4*)(x + (size_t)n * FIN + c4 * 4);
    *(float4*)(&xs[r * XS_STRIDE + c4 * 4]) = v;
  }
  __syncthreads();

  int cg = t & 15;
  int ng = t >> 4;
  int c0 = cg * 8;

  float acc[4][8];
  #pragma unroll
  for (int i = 0; i < 4; ++i)
    #pragma unroll
    for (int j = 0; j < 8; ++j) acc[i][j] = 0.f;

  for (int k0 = 0; k0 < FIN; k0 += 4) {
    float xr[4][4];
    #pragma unroll
    for (int i = 0; i < 4; ++i)
      *(float4*)xr[i] = *(const float4*)&xs[(ng * 4 + i) * XS_STRIDE + k0];
    #pragma unroll
    for (int kk = 0; kk < 4; ++kk) {
      float4 w0 = *(const float4*)(W1 + (k0 + kk) * FOUT + c0);
      float4 w1 = *(const float4*)(W1 + (k0 + kk) * FOUT + c0 + 4);
      float wv[8] = {w0.x, w0.y, w0.z, w0.w, w1.x, w1.y, w1.z, w1.w};
      #pragma unroll
      for (int i = 0; i < 4; ++i) {
        float xv = xr[i][kk];
        #pragma unroll
        for (int j = 0; j < 8; ++j) acc[i][j] = fmaf(xv, wv[j], acc[i][j]);
      }
    }
  }

  int head = cg >> 2;
  float vs[4], vd[4], rmax[4];
  #pragma unroll
  for (int i = 0; i < 4; ++i) {
    float s = 0.f, d = 0.f, m = 0.f;
    #pragma unroll
    for (int j = 0; j < 8; ++j) {
      s = fmaf(acc[i][j], asw[c0 + j], s);
      d = fmaf(acc[i][j], adw[c0 + j], d);
      m = fmaxf(m, fabsf(acc[i][j]));
    }
    vs[i] = s; vd[i] = d; rmax[i] = m;
  }
  // rowmax over all 16 channel-groups (lanes differing in bits 0..3)
  #pragma unroll
  for (int i = 0; i < 4; ++i) {
    rmax[i] = fmaxf(rmax[i], __shfl_xor(rmax[i], 1, 64));
    rmax[i] = fmaxf(rmax[i], __shfl_xor(rmax[i], 2, 64));
    rmax[i] = fmaxf(rmax[i], __shfl_xor(rmax[i], 4, 64));
    rmax[i] = fmaxf(rmax[i], __shfl_xor(rmax[i], 8, 64));
  }
  #pragma unroll
  for (int i = 0; i < 4; ++i) {
    int n = nb + ng * 4 + i;
    if (n >= NN) continue;
    float rm = fmaxf(rmax[i], 1e-30f);
    float inv = 127.f / rm;
    unsigned b[8];
    #pragma unroll
    for (int j = 0; j < 8; ++j) {
      float qf = fminf(127.f, fmaxf(-127.f, rintf(acc[i][j] * inv)));
      b[j] = (unsigned)((int)qf) & 0xffu;
    }
    uint2 pk;
    pk.x = b[0] | (b[1] << 8) | (b[2] << 16) | (b[3] << 24);
    pk.y = b[4] | (b[5] << 8) | (b[6] << 16) | (b[7] << 24);
    *(uint2*)(h8 + (size_t)n * FOUT + c0) = pk;
    if (cg == 0) hscale[n] = rm / 127.f;
  }
  #pragma unroll
  for (int i = 0; i < 4; ++i) {
    vs[i] += __shfl_xor(vs[i], 1, 64); vs[i] += __shfl_xor(vs[i], 2, 64);
    vd[i] += __shfl_xor(vd[i], 1, 64); vd[i] += __shfl_xor(vd[i], 2, 64);
  }
  if ((cg & 3) == 0) {
    #pragma unroll
    for (int i = 0; i < 4; ++i) {
      int n = nb + ng * 4 + i;
      if (n < NN) { as1[n * 4 + head] = vs[i]; ad1[n * 4 + head] = vd[i]; }
    }
  }
}

// ---------------- CSR build (by dst) ----------------
__global__ __launch_bounds__(256) void k_init(int* __restrict__ deg) {
  int i = blockIdx.x * 256 + threadIdx.x;
  if (i < NN) deg[i] = 1;   // self loop
}

__global__ __launch_bounds__(256) void k_hist(const int* __restrict__ ei, int* __restrict__ deg) {
  int i = blockIdx.x * 256 + threadIdx.x;
  if (i < EE) atomicAdd(&deg[ei[EE + i]], 1);
}

__global__ __launch_bounds__(1024) void k_scanA(const int* __restrict__ deg,
    int* __restrict__ cur, int* __restrict__ bsum) {
  __shared__ int sums[1024];
  int t = threadIdx.x;
  int idx = blockIdx.x * 1024 + t;
  int v = (idx < NN) ? deg[idx] : 0;
  sums[t] = v; __syncthreads();
  #pragma unroll
  for (int off = 1; off < 1024; off <<= 1) {
    int u = (t >= off) ? sums[t - off] : 0;
    __syncthreads();
    sums[t] += u;
    __syncthreads();
  }
  if (idx < NN) cur[idx] = sums[t] - v;        // exclusive within block
  if (t == 1023) bsum[blockIdx.x] = sums[1023];
}

__global__ __launch_bounds__(1024) void k_scanB(const int* __restrict__ bsum,
    int* __restrict__ offs, int* __restrict__ cur) {
  int b = blockIdx.x;
  int t = threadIdx.x;
  int base = 0;
  for (int i = 0; i < SCB; ++i) base += (i < b) ? bsum[i] : 0;
  int idx = b * 1024 + t;
  if (idx < NN) {
    int v = cur[idx] + base;
    offs[idx] = v;
    cur[idx] = v;
  }
  if (b == SCB - 1 && t == 0) {
    int total = base;
    for (int i = b; i < SCB; ++i) total += bsum[i];
    offs[NN] = total;   // = EE + NN
  }
}

// dst-range-partitioned scatter (XCD L2 locality)
__global__ __launch_bounds__(256) void k_scatter(const int* __restrict__ ei,
    int* __restrict__ cur, int* __restrict__ csr) {
  int part = blockIdx.x & (NPART - 1);
  int blk  = blockIdx.x >> 3;
  int nblk = gridDim.x >> 3;
  int lo = part * PSZ, hi = lo + PSZ;

  for (int i = blk * 256 + threadIdx.x; i < EE; i += nblk * 256) {
    int d = ei[EE + i];
    if (d >= lo && d < hi) {
      int s = ei[i];
      int p = atomicAdd(&cur[d], 1);
      csr[p] = s;
    }
  }
  for (int n = lo + blk * 256 + threadIdx.x; n < hi; n += nblk * 256) {
    int p = atomicAdd(&cur[n], 1);
    csr[p] = n;
  }
}

// ---------------- conv1 aggregation (no-max softmax, int8 h) + BN + leaky + conv2 proj ----------------
__global__ __launch_bounds__(256) void k_agg1(
    const int* __restrict__ offs, const int* __restrict__ csr,
    const signed char* __restrict__ h8, const float* __restrict__ hscale,
    const float* __restrict__ as1, const float* __restrict__ ad1,
    const float* __restrict__ bias1, const float* __restrict__ gamma, const float* __restrict__ beta,
    const float* __restrict__ mean, const float* __restrict__ var,
    const float* __restrict__ W2, const float* __restrict__ asw2, const float* __restrict__ adw2,
    float* __restrict__ h2, float* __restrict__ as2, float* __restrict__ ad2) {
  int wid = threadIdx.x >> 6;
  int lane = threadIdx.x & 63;
  int n = blockIdx.x * 4 + wid;
  if (n >= NN) return;
  int r0 = offs[n], r1 = offs[n + 1];
  int hh = lane >> 4;
  float ad = ad1[n * 4 + hh];
  const unsigned short* hp = (const unsigned short*)h8;  // 2 int8 channels per ushort

  float acc0 = 0.f, acc1 = 0.f, den = 0.f;
  #pragma unroll 2
  for (int i = r0; i < r1; ++i) {
    int s = csr[i];
    float e = as1[s * 4 + hh] + ad;
    e = e > 0.f ? e : NEG * e;
    float ex = __expf(e);
    den += ex;
    float w = ex * hscale[s];
    unsigned int pv = hp[s * 64 + lane];
    int q0 = ((int)(pv << 24)) >> 24;
    int q1 = ((int)(pv << 16)) >> 24;
    acc0 = fmaf(w, (float)q0, acc0);
    acc1 = fmaf(w, (float)q1, acc1);
  }

  int c0 = lane * 2, c1 = lane * 2 + 1;
  float inv = 1.f / den;
  float o0 = acc0 * inv + bias1[c0];
  float o1 = acc1 * inv + bias1[c1];
  o0 = gamma[c0] * (o0 - mean[c0]) * rsqrtf(var[c0] + BNEPS) + beta[c0];
  o1 = gamma[c1] * (o1 - mean[c1]) * rsqrtf(var[c1] + BNEPS) + beta[c1];
  o0 = o0 > 0.f ? o0 : NEG * o0;
  o1 = o1 > 0.f ? o1 : NEG * o1;

  float p0 = o0 * W2[c0 * 2 + 0] + o1 * W2[c1 * 2 + 0];
  float p1 = o0 * W2[c0 * 2 + 1] + o1 * W2[c1 * 2 + 1];
  #pragma unroll
  for (int mm = 32; mm >= 1; mm >>= 1) {
    p0 += __shfl_xor(p0, mm, 64);
    p1 += __shfl_xor(p1, mm, 64);
  }
  if (lane == 0) {
    h2[n * 2 + 0] = p0;
    h2[n * 2 + 1] = p1;
    as2[n] = p0 * asw2[0] + p1 * asw2[1];
    ad2[n] = p0 * adw2[0] + p1 * adw2[1];
  }
}

// ---------------- conv2 aggregation (no-max softmax) + bias + log_softmax ----------------
__global__ __launch_bounds__(256) void k_agg2(
    const int* __restrict__ offs, const int* __restrict__ csr,
    const float* __restrict__ h2, const float* __restrict__ as2, const float* __restrict__ ad2,
    const float* __restrict__ bias2, float* __restrict__ out) {
  int wid = threadIdx.x >> 6;
  int lane = threadIdx.x & 63;
  int n = blockIdx.x * 4 + wid;
  if (n >= NN) return;
  int r0 = offs[n], r1 = offs[n + 1];
  float ad = ad2[n];

  float den = 0.f, a0 = 0.f, a1 = 0.f;
  for (int i = r0 + lane; i < r1; i += 64) {
    int s = csr[i];
    float e = as2[s] + ad; e = e > 0.f ? e : NEG * e;
    float ex = __expf(e);
    float2 hv = *(const float2*)(h2 + s * 2);
    den += ex;
    a0 = fmaf(ex, hv.x, a0);
    a1 = fmaf(ex, hv.y, a1);
  }
  #pragma unroll
  for (int mm = 32; mm >= 1; mm >>= 1) {
    den += __shfl_xor(den, mm, 64);
    a0  += __shfl_xor(a0, mm, 64);
    a1  += __shfl_xor(a1, mm, 64);
  }
  if (lane == 0) {
    float o0 = a0 / den + bias2[0];
    float o1 = a1 / den + bias2[1];
    float mx = fmaxf(o0, o1);
    float lse = mx + logf(__expf(o0 - mx) + __expf(o1 - mx));
    out[n * 2 + 0] = o0 - lse;
    out[n * 2 + 1] = o1 - lse;
  }
}

extern "C" void kernel_launch(void* const* d_in, const int* in_sizes, int n_in,
                              void* d_out, int out_size, void* d_ws, size_t ws_size,
                              hipStream_t stream) {
  const float* x     = (const float*)d_in[0];
  const int*   ei    = (const int*)d_in[1];
  const float* W1    = (const float*)d_in[2];
  const float* asw1  = (const float*)d_in[3];
  const float* adw1  = (const float*)d_in[4];
  const float* bias1 = (const float*)d_in[5];
  const float* gamma = (const float*)d_in[6];
  const float* beta  = (const float*)d_in[7];
  const float* mean  = (const float*)d_in[8];
  const float* var   = (const float*)d_in[9];
  const float* W2    = (const float*)d_in[10];
  const float* asw2  = (const float*)d_in[11];
  const float* adw2  = (const float*)d_in[12];
  const float* bias2 = (const float*)d_in[13];
  float* out = (float*)d_out;

  char* ws = (char*)d_ws;
  size_t off = 0;
  auto alloc = [&](size_t bytes) {
    void* p = ws + off;
    off += (bytes + 255) & ~(size_t)255;
    return p;
  };
  signed char* h8 = (signed char*)alloc((size_t)NN * FOUT);   // 6.4 MB int8
  float* hscale = (float*)alloc((size_t)NN * 4);              // 200 KB
  float* as1  = (float*)alloc((size_t)NN * 4 * 4);
  float* ad1  = (float*)alloc((size_t)NN * 4 * 4);
  int*   deg  = (int*)alloc((size_t)NN * 4);
  int*   offs = (int*)alloc(((size_t)NN + 1) * 4);
  int*   cur  = (int*)alloc((size_t)NN * 4);
  int*   bsum = (int*)alloc((size_t)SCB * 4);
  int*   csr  = (int*)alloc((size_t)(EE + NN) * 4);
  float* h2   = (float*)alloc((size_t)NN * 2 * 4);
  float* as2  = (float*)alloc((size_t)NN * 4);
  float* ad2  = (float*)alloc((size_t)NN * 4);
  (void)ws_size; (void)in_sizes; (void)n_in; (void)out_size;

  k_proj   <<<(NN + 63) / 64, 256, 0, stream>>>(x, W1, asw1, adw1, h8, hscale, as1, ad1);
  k_init   <<<(NN + 255) / 256, 256, 0, stream>>>(deg);
  k_hist   <<<(EE + 255) / 256, 256, 0, stream>>>(ei, deg);
  k_scanA  <<<SCB, 1024, 0, stream>>>(deg, cur, bsum);
  k_scanB  <<<SCB, 1024, 0, stream>>>(bsum, offs, cur);
  k_scatter<<<2048, 256, 0, stream>>>(ei, cur, csr);
  k_agg1   <<<(NN + 3) / 4, 256, 0, stream>>>(offs, csr, h8, hscale, as1, ad1, bias1, gamma, beta,
                                              mean, var, W2, asw2, adw2, h2, as2, ad2);
  k_agg2   <<<(NN + 3) / 4, 256, 0, stream>>>(offs, csr, h2, as2, ad2, bias2, out);
}

// Round 7
// 284.026 us; speedup vs baseline: 2.5290x; 1.1016x over previous
//
#include <hip/hip_runtime.h>
#include <math.h>

#define NN 50000
#define EE 1600000
#define FIN 128
#define FOUT 128   // HEADS*HID
#define NEG 0.2f
#define BNEPS 1e-5f

#define NPART 8
#define PSZ (NN / NPART)   // 6250

#define SCB 49             // scan blocks (49*1024 >= 50000)

// float -> bf16 (round-to-nearest-even), branch-free
static __device__ __forceinline__ unsigned f2bf(float f) {
  unsigned int u = __float_as_uint(f);
  u += 0x7fffu + ((u >> 16) & 1u);
  return u >> 16;
}

// ---------------- conv1 projection + attention logits (register-tiled GEMM) ----------------
// h stored int8 with per-row scale: h[n][c] ~= q[n][c] * hscale[n].
#define XS_STRIDE 132
__global__ __launch_bounds__(256) void k_proj(const float* __restrict__ x,
    const float* __restrict__ W1, const float* __restrict__ asw, const float* __restrict__ adw,
    signed char* __restrict__ h8, float* __restrict__ hscale,
    float* __restrict__ as1, float* __restrict__ ad1) {
  __shared__ float xs[64 * XS_STRIDE];
  int t = threadIdx.x;
  int nb = blockIdx.x * 64;

  #pragma unroll
  for (int j = 0; j < 8; ++j) {
    int idx = t + 256 * j;
    int r = idx >> 5;
    int c4 = idx & 31;
    int n = nb + r; if (n >= NN) n = NN - 1;
    float4 v = *(const float4*)(x + (size_t)n * FIN + c4 * 4);
    *(float4*)(&xs[r * XS_STRIDE + c4 * 4]) = v;
  }
  __syncthreads();

  int cg = t & 15;
  int ng = t >> 4;
  int c0 = cg * 8;

  float acc[4][8];
  #pragma unroll
  for (int i = 0; i < 4; ++i)
    #pragma unroll
    for (int j = 0; j < 8; ++j) acc[i][j] = 0.f;

  for (int k0 = 0; k0 < FIN; k0 += 4) {
    float xr[4][4];
    #pragma unroll
    for (int i = 0; i < 4; ++i)
      *(float4*)xr[i] = *(const float4*)&xs[(ng * 4 + i) * XS_STRIDE + k0];
    #pragma unroll
    for (int kk = 0; kk < 4; ++kk) {
      float4 w0 = *(const float4*)(W1 + (k0 + kk) * FOUT + c0);
      float4 w1 = *(const float4*)(W1 + (k0 + kk) * FOUT + c0 + 4);
      float wv[8] = {w0.x, w0.y, w0.z, w0.w, w1.x, w1.y, w1.z, w1.w};
      #pragma unroll
      for (int i = 0; i < 4; ++i) {
        float xv = xr[i][kk];
        #pragma unroll
        for (int j = 0; j < 8; ++j) acc[i][j] = fmaf(xv, wv[j], acc[i][j]);
      }
    }
  }

  int head = cg >> 2;
  float vs[4], vd[4], rmax[4];
  #pragma unroll
  for (int i = 0; i < 4; ++i) {
    float s = 0.f, d = 0.f, m = 0.f;
    #pragma unroll
    for (int j = 0; j < 8; ++j) {
      s = fmaf(acc[i][j], asw[c0 + j], s);
      d = fmaf(acc[i][j], adw[c0 + j], d);
      m = fmaxf(m, fabsf(acc[i][j]));
    }
    vs[i] = s; vd[i] = d; rmax[i] = m;
  }
  #pragma unroll
  for (int i = 0; i < 4; ++i) {
    rmax[i] = fmaxf(rmax[i], __shfl_xor(rmax[i], 1, 64));
    rmax[i] = fmaxf(rmax[i], __shfl_xor(rmax[i], 2, 64));
    rmax[i] = fmaxf(rmax[i], __shfl_xor(rmax[i], 4, 64));
    rmax[i] = fmaxf(rmax[i], __shfl_xor(rmax[i], 8, 64));
  }
  #pragma unroll
  for (int i = 0; i < 4; ++i) {
    int n = nb + ng * 4 + i;
    if (n >= NN) continue;
    float rm = fmaxf(rmax[i], 1e-30f);
    float inv = 127.f / rm;
    unsigned b[8];
    #pragma unroll
    for (int j = 0; j < 8; ++j) {
      float qf = fminf(127.f, fmaxf(-127.f, rintf(acc[i][j] * inv)));
      b[j] = (unsigned)((int)qf) & 0xffu;
    }
    uint2 pk;
    pk.x = b[0] | (b[1] << 8) | (b[2] << 16) | (b[3] << 24);
    pk.y = b[4] | (b[5] << 8) | (b[6] << 16) | (b[7] << 24);
    *(uint2*)(h8 + (size_t)n * FOUT + c0) = pk;
    if (cg == 0) hscale[n] = rm / 127.f;
  }
  #pragma unroll
  for (int i = 0; i < 4; ++i) {
    vs[i] += __shfl_xor(vs[i], 1, 64); vs[i] += __shfl_xor(vs[i], 2, 64);
    vd[i] += __shfl_xor(vd[i], 1, 64); vd[i] += __shfl_xor(vd[i], 2, 64);
  }
  if ((cg & 3) == 0) {
    #pragma unroll
    for (int i = 0; i < 4; ++i) {
      int n = nb + ng * 4 + i;
      if (n < NN) { as1[n * 4 + head] = vs[i]; ad1[n * 4 + head] = vd[i]; }
    }
  }
}

// ---------------- CSR build (by dst) ----------------
__global__ __launch_bounds__(256) void k_init(int* __restrict__ deg) {
  int i = blockIdx.x * 256 + threadIdx.x;
  if (i < NN) deg[i] = 1;   // self loop
}

__global__ __launch_bounds__(256) void k_hist(const int* __restrict__ ei, int* __restrict__ deg) {
  int i = blockIdx.x * 256 + threadIdx.x;
  if (i < EE) atomicAdd(&deg[ei[EE + i]], 1);
}

__global__ __launch_bounds__(1024) void k_scanA(const int* __restrict__ deg,
    int* __restrict__ cur, int* __restrict__ bsum) {
  __shared__ int sums[1024];
  int t = threadIdx.x;
  int idx = blockIdx.x * 1024 + t;
  int v = (idx < NN) ? deg[idx] : 0;
  sums[t] = v; __syncthreads();
  #pragma unroll
  for (int off = 1; off < 1024; off <<= 1) {
    int u = (t >= off) ? sums[t - off] : 0;
    __syncthreads();
    sums[t] += u;
    __syncthreads();
  }
  if (idx < NN) cur[idx] = sums[t] - v;        // exclusive within block
  if (t == 1023) bsum[blockIdx.x] = sums[1023];
}

__global__ __launch_bounds__(1024) void k_scanB(const int* __restrict__ bsum,
    int* __restrict__ offs, int* __restrict__ cur) {
  int b = blockIdx.x;
  int t = threadIdx.x;
  int base = 0;
  for (int i = 0; i < SCB; ++i) base += (i < b) ? bsum[i] : 0;
  int idx = b * 1024 + t;
  if (idx < NN) {
    int v = cur[idx] + base;
    offs[idx] = v;
    cur[idx] = v;
  }
  if (b == SCB - 1 && t == 0) {
    int total = base;
    for (int i = b; i < SCB; ++i) total += bsum[i];
    offs[NN] = total;   // = EE + NN
  }
}

// edge weight: packed bf16 ex[h]=exp(lrelu(as1[s][h]+ad1[d][h])) for h=0..3
static __device__ __forceinline__ uint2 edge_w(const float* as1, const float* ad1, int s, int d) {
  float4 a = *(const float4*)(as1 + s * 4);
  float4 b = *(const float4*)(ad1 + d * 4);
  float e0 = a.x + b.x; e0 = e0 > 0.f ? e0 : NEG * e0;
  float e1 = a.y + b.y; e1 = e1 > 0.f ? e1 : NEG * e1;
  float e2 = a.z + b.z; e2 = e2 > 0.f ? e2 : NEG * e2;
  float e3 = a.w + b.w; e3 = e3 > 0.f ? e3 : NEG * e3;
  uint2 pk;
  pk.x = f2bf(__expf(e0)) | (f2bf(__expf(e1)) << 16);
  pk.y = f2bf(__expf(e2)) | (f2bf(__expf(e3)) << 16);
  return pk;
}

// dst-range-partitioned scatter (XCD L2 locality) + edge-parallel softmax weight precompute
__global__ __launch_bounds__(256) void k_scatter(const int* __restrict__ ei,
    int* __restrict__ cur, int* __restrict__ csr, uint2* __restrict__ ew2,
    const float* __restrict__ as1, const float* __restrict__ ad1) {
  int part = blockIdx.x & (NPART - 1);
  int blk  = blockIdx.x >> 3;
  int nblk = gridDim.x >> 3;
  int lo = part * PSZ, hi = lo + PSZ;

  for (int i = blk * 256 + threadIdx.x; i < EE; i += nblk * 256) {
    int d = ei[EE + i];
    if (d >= lo && d < hi) {
      int s = ei[i];
      int p = atomicAdd(&cur[d], 1);
      csr[p] = s;
      ew2[p] = edge_w(as1, ad1, s, d);
    }
  }
  for (int n = lo + blk * 256 + threadIdx.x; n < hi; n += nblk * 256) {
    int p = atomicAdd(&cur[n], 1);
    csr[p] = n;
    ew2[p] = edge_w(as1, ad1, n, n);
  }
}

// ---------------- conv1 aggregation + BN + leaky + conv2 projection ----------------
// Wave-serial edge loop with all scalar work hoisted: weights precomputed (ew2),
// tile-16 preload + readlane broadcast; per edge only the int8 h gather + 2 FMA/lane.
#define AGG_BODY(J)                                                                  \
  {                                                                                  \
    int s = __builtin_amdgcn_readlane(sv, (J));                                      \
    float hs = __uint_as_float((unsigned)__builtin_amdgcn_readlane(hv_i, (J)));      \
    unsigned wlo = (unsigned)__builtin_amdgcn_readlane(ewx, (J));                    \
    unsigned whi = (unsigned)__builtin_amdgcn_readlane(ewy, (J));                    \
    unsigned wsel = selhi ? whi : wlo;                                               \
    float ex = __uint_as_float((wsel << shiftv) & 0xffff0000u);                      \
    den += ex;                                                                       \
    float w = ex * hs;                                                               \
    unsigned pv = hp[(size_t)s * 64 + lane];                                         \
    int q0 = ((int)(pv << 24)) >> 24;                                                \
    int q1 = ((int)(pv << 16)) >> 24;                                                \
    acc0 = fmaf(w, (float)q0, acc0);                                                 \
    acc1 = fmaf(w, (float)q1, acc1);                                                 \
  }

__global__ __launch_bounds__(256) void k_agg1(
    const int* __restrict__ offs, const int* __restrict__ csr, const uint2* __restrict__ ew2,
    const signed char* __restrict__ h8, const float* __restrict__ hscale,
    const float* __restrict__ bias1, const float* __restrict__ gamma, const float* __restrict__ beta,
    const float* __restrict__ mean, const float* __restrict__ var,
    const float* __restrict__ W2, const float* __restrict__ asw2, const float* __restrict__ adw2,
    float* __restrict__ h2, float* __restrict__ as2, float* __restrict__ ad2) {
  int wid = threadIdx.x >> 6;
  int lane = threadIdx.x & 63;
  int n = blockIdx.x * 4 + wid;
  if (n >= NN) return;
  int r0 = offs[n], r1 = offs[n + 1];
  int hh = lane >> 4;                 // head of this lane's channel pair
  int ej = lane & 15;                 // tile slot this lane preloads
  int shiftv = (hh & 1) ? 0 : 16;     // bf16 extract shift for this head
  bool selhi = hh >= 2;
  const unsigned short* hp = (const unsigned short*)h8;

  float acc0 = 0.f, acc1 = 0.f, den = 0.f;

  int base = r0;
  for (; base + 16 <= r1; base += 16) {
    int idx = base + ej;
    int sv = csr[idx];
    int hv_i = (int)__float_as_uint(hscale[sv]);
    uint2 ev = ew2[idx];
    int ewx = (int)ev.x, ewy = (int)ev.y;
    #pragma unroll
    for (int j = 0; j < 16; ++j) AGG_BODY(j)
  }
  int m = r1 - base;
  if (m > 0) {
    int idx = base + (ej < m ? ej : m - 1);
    int sv = csr[idx];
    int hv_i = (int)__float_as_uint(hscale[sv]);
    uint2 ev = ew2[idx];
    int ewx = (int)ev.x, ewy = (int)ev.y;
    for (int j = 0; j < m; ++j) AGG_BODY(j)
  }

  // den is already the full per-head sum in every lane (each lane accumulated all edges)
  int c0 = lane * 2, c1 = lane * 2 + 1;
  float inv = 1.f / den;
  float o0 = acc0 * inv + bias1[c0];
  float o1 = acc1 * inv + bias1[c1];
  o0 = gamma[c0] * (o0 - mean[c0]) * rsqrtf(var[c0] + BNEPS) + beta[c0];
  o1 = gamma[c1] * (o1 - mean[c1]) * rsqrtf(var[c1] + BNEPS) + beta[c1];
  o0 = o0 > 0.f ? o0 : NEG * o0;
  o1 = o1 > 0.f ? o1 : NEG * o1;

  float p0 = o0 * W2[c0 * 2 + 0] + o1 * W2[c1 * 2 + 0];
  float p1 = o0 * W2[c0 * 2 + 1] + o1 * W2[c1 * 2 + 1];
  #pragma unroll
  for (int mm = 32; mm >= 1; mm >>= 1) {
    p0 += __shfl_xor(p0, mm, 64);
    p1 += __shfl_xor(p1, mm, 64);
  }
  if (lane == 0) {
    h2[n * 2 + 0] = p0;
    h2[n * 2 + 1] = p1;
    as2[n] = p0 * asw2[0] + p1 * asw2[1];
    ad2[n] = p0 * adw2[0] + p1 * adw2[1];
  }
}

// ---------------- conv2 aggregation (no-max softmax) + bias + log_softmax ----------------
__global__ __launch_bounds__(256) void k_agg2(
    const int* __restrict__ offs, const int* __restrict__ csr,
    const float* __restrict__ h2, const float* __restrict__ as2, const float* __restrict__ ad2,
    const float* __restrict__ bias2, float* __restrict__ out) {
  int wid = threadIdx.x >> 6;
  int lane = threadIdx.x & 63;
  int n = blockIdx.x * 4 + wid;
  if (n >= NN) return;
  int r0 = offs[n], r1 = offs[n + 1];
  float ad = ad2[n];

  float den = 0.f, a0 = 0.f, a1 = 0.f;
  for (int i = r0 + lane; i < r1; i += 64) {
    int s = csr[i];
    float e = as2[s] + ad; e = e > 0.f ? e : NEG * e;
    float ex = __expf(e);
    float2 hv = *(const float2*)(h2 + s * 2);
    den += ex;
    a0 = fmaf(ex, hv.x, a0);
    a1 = fmaf(ex, hv.y, a1);
  }
  #pragma unroll
  for (int mm = 32; mm >= 1; mm >>= 1) {
    den += __shfl_xor(den, mm, 64);
    a0  += __shfl_xor(a0, mm, 64);
    a1  += __shfl_xor(a1, mm, 64);
  }
  if (lane == 0) {
    float o0 = a0 / den + bias2[0];
    float o1 = a1 / den + bias2[1];
    float mx = fmaxf(o0, o1);
    float lse = mx + logf(__expf(o0 - mx) + __expf(o1 - mx));
    out[n * 2 + 0] = o0 - lse;
    out[n * 2 + 1] = o1 - lse;
  }
}

extern "C" void kernel_launch(void* const* d_in, const int* in_sizes, int n_in,
                              void* d_out, int out_size, void* d_ws, size_t ws_size,
                              hipStream_t stream) {
  const float* x     = (const float*)d_in[0];
  const int*   ei    = (const int*)d_in[1];
  const float* W1    = (const float*)d_in[2];
  const float* asw1  = (const float*)d_in[3];
  const float* adw1  = (const float*)d_in[4];
  const float* bias1 = (const float*)d_in[5];
  const float* gamma = (const float*)d_in[6];
  const float* beta  = (const float*)d_in[7];
  const float* mean  = (const float*)d_in[8];
  const float* var   = (const float*)d_in[9];
  const float* W2    = (const float*)d_in[10];
  const float* asw2  = (const float*)d_in[11];
  const float* adw2  = (const float*)d_in[12];
  const float* bias2 = (const float*)d_in[13];
  float* out = (float*)d_out;

  char* ws = (char*)d_ws;
  size_t off = 0;
  auto alloc = [&](size_t bytes) {
    void* p = ws + off;
    off += (bytes + 255) & ~(size_t)255;
    return p;
  };
  signed char* h8 = (signed char*)alloc((size_t)NN * FOUT);   // 6.4 MB int8
  float* hscale = (float*)alloc((size_t)NN * 4);
  float* as1  = (float*)alloc((size_t)NN * 4 * 4);
  float* ad1  = (float*)alloc((size_t)NN * 4 * 4);
  int*   deg  = (int*)alloc((size_t)NN * 4);
  int*   offs = (int*)alloc(((size_t)NN + 1) * 4);
  int*   cur  = (int*)alloc((size_t)NN * 4);
  int*   bsum = (int*)alloc((size_t)SCB * 4);
  int*   csr  = (int*)alloc((size_t)(EE + NN) * 4);           // 6.6 MB
  uint2* ew2  = (uint2*)alloc((size_t)(EE + NN) * 8);         // 13.2 MB
  float* h2   = (float*)alloc((size_t)NN * 2 * 4);
  float* as2  = (float*)alloc((size_t)NN * 4);
  float* ad2  = (float*)alloc((size_t)NN * 4);
  (void)ws_size; (void)in_sizes; (void)n_in; (void)out_size;

  k_proj   <<<(NN + 63) / 64, 256, 0, stream>>>(x, W1, asw1, adw1, h8, hscale, as1, ad1);
  k_init   <<<(NN + 255) / 256, 256, 0, stream>>>(deg);
  k_hist   <<<(EE + 255) / 256, 256, 0, stream>>>(ei, deg);
  k_scanA  <<<SCB, 1024, 0, stream>>>(deg, cur, bsum);
  k_scanB  <<<SCB, 1024, 0, stream>>>(bsum, offs, cur);
  k_scatter<<<2048, 256, 0, stream>>>(ei, cur, csr, ew2, as1, ad1);
  k_agg1   <<<(NN + 3) / 4, 256, 0, stream>>>(offs, csr, ew2, h8, hscale, bias1, gamma, beta,
                                              mean, var, W2, asw2, adw2, h2, as2, ad2);
  k_agg2   <<<(NN + 3) / 4, 256, 0, stream>>>(offs, csr, h2, as2, ad2, bias2, out);
}